// Round 1
// baseline (312.513 us; speedup 1.0000x reference)
//
#include <hip/hip_runtime.h>
#include <hip/hip_bf16.h>

#define N_NODES 50000
#define NE      400000
#define NB      196        // ceil(50000/256)
#define AGG_B   12500      // 50000/4 waves per type

struct P {
    const float *x_user, *x_item;
    const int   *ei_u2i, *ei_i2u;
    const float *w_src_u2i, *w_dst_u2i, *att_src_u2i, *att_dst_u2i, *b_u2i;
    const float *w_src_i2u, *w_dst_i2u, *att_src_i2u, *att_dst_i2u, *b_i2u;
    const float *ln_g_user, *ln_b_user, *ln_g_item, *ln_b_item;
    float *hs0, *hs1;                 // hs_u2i (from x_user), hs_i2u (from x_item)
    float *as0, *ad0, *as1, *ad1;     // per-node attn scalars [N,2]
    float *v_s0, *v_d0, *v_s1, *v_d1; // folded att vectors [128*2]
    int   *cnt0, *cnt1, *off0, *off1, *cur0, *cur1;
    int   *bsum;                      // [2*256]
    int   *srcs0, *srcs1;
    float *tv0, *tv1;                 // float2 per CSR slot
    float *out_user, *out_item;
};

// ---- fold v[k,h] = sum_c w[k, h*64+c] * att[h,c] : 4 blocks x 256 threads ----
__global__ void fold_v(P p) {
    int b = blockIdx.x;
    const float* w   = b==0? p.w_src_u2i : b==1? p.w_dst_u2i : b==2? p.w_src_i2u : p.w_dst_i2u;
    const float* att = b==0? p.att_src_u2i : b==1? p.att_dst_u2i : b==2? p.att_src_i2u : p.att_dst_i2u;
    float* v         = b==0? p.v_s0 : b==1? p.v_d0 : b==2? p.v_s1 : p.v_d1;
    int k = threadIdx.x >> 1, h = threadIdx.x & 1;
    float s = 0.f;
    for (int c = 0; c < 64; ++c) s += w[k*128 + h*64 + c] * att[h*64 + c];
    v[k*2 + h] = s;
}

// ---- fp32 GEMM: C[M,128] = A[M,128] @ W[128,128], 64-row tiles ----
__global__ __launch_bounds__(256) void gemm128(const float* __restrict__ A,
                                               const float* __restrict__ W,
                                               float* __restrict__ C, int M) {
    __shared__ float Xs[128][68];   // k-major (transposed), padded
    __shared__ float Ws[32][128];
    int tid = threadIdx.x;
    int m0 = blockIdx.x * 64;
    // load X tile transposed (coalesced float4 reads)
    for (int i = 0; i < 8; ++i) {
        int f = tid + i * 256;
        int row = f >> 5;            // 32 float4 per row
        int k4  = (f & 31) << 2;
        float4 v = make_float4(0.f, 0.f, 0.f, 0.f);
        if (m0 + row < M) v = *(const float4*)(A + (size_t)(m0 + row) * 128 + k4);
        Xs[k4+0][row] = v.x; Xs[k4+1][row] = v.y; Xs[k4+2][row] = v.z; Xs[k4+3][row] = v.w;
    }
    float acc[4][8];
#pragma unroll
    for (int r = 0; r < 4; ++r)
#pragma unroll
        for (int j = 0; j < 8; ++j) acc[r][j] = 0.f;
    int rb = tid >> 4;     // 0..15 row group of 4
    int cb = tid & 15;     // 0..15 col group of 8
    int c0 = cb * 8;
    for (int kp = 0; kp < 4; ++kp) {
        __syncthreads();
        for (int i = 0; i < 4; ++i) {
            int f = tid + i * 256;
            int kk = f >> 5;
            int c4 = (f & 31) << 2;
            *(float4*)&Ws[kk][c4] = *(const float4*)(W + (size_t)(kp*32 + kk)*128 + c4);
        }
        __syncthreads();
#pragma unroll
        for (int k = 0; k < 32; ++k) {
            float4 w0 = *(float4*)&Ws[k][c0];
            float4 w1 = *(float4*)&Ws[k][c0+4];
            float4 xa = *(float4*)&Xs[kp*32 + k][rb*4];
            float xr[4] = {xa.x, xa.y, xa.z, xa.w};
            float wv[8] = {w0.x,w0.y,w0.z,w0.w,w1.x,w1.y,w1.z,w1.w};
#pragma unroll
            for (int r = 0; r < 4; ++r)
#pragma unroll
                for (int j = 0; j < 8; ++j) acc[r][j] += xr[r] * wv[j];
        }
    }
    for (int r = 0; r < 4; ++r) {
        int row = m0 + rb*4 + r;
        if (row < M) {
            *(float4*)(C + (size_t)row*128 + c0)     = make_float4(acc[r][0],acc[r][1],acc[r][2],acc[r][3]);
            *(float4*)(C + (size_t)row*128 + c0 + 4) = make_float4(acc[r][4],acc[r][5],acc[r][6],acc[r][7]);
        }
    }
}

// ---- skinny matvecs: per x, two [128x2] projections ----
__global__ void skinny(P p) {
    int t   = blockIdx.x / NB;
    int row = (blockIdx.x % NB) * 256 + threadIdx.x;
    if (row >= N_NODES) return;
    const float* x  = t ? p.x_item : p.x_user;
    const float* va = t ? p.v_d0 : p.v_s0;  // x_user->a_s(u2i), x_item->a_d(u2i)
    const float* vb = t ? p.v_s1 : p.v_d1;  // x_user->a_d(i2u), x_item->a_s(i2u)
    float* oa = t ? p.ad0 : p.as0;
    float* ob = t ? p.as1 : p.ad1;
    const float4* xr = (const float4*)(x + (size_t)row * 128);
    const float2* va2 = (const float2*)va;
    const float2* vb2 = (const float2*)vb;
    float a0=0.f, a1=0.f, b0=0.f, b1=0.f;
    for (int i = 0; i < 32; ++i) {
        float4 xv = xr[i];
        float xs[4] = {xv.x, xv.y, xv.z, xv.w};
#pragma unroll
        for (int u = 0; u < 4; ++u) {
            float2 fa = va2[i*4 + u];
            float2 fb = vb2[i*4 + u];
            a0 += xs[u]*fa.x; a1 += xs[u]*fa.y;
            b0 += xs[u]*fb.x; b1 += xs[u]*fb.y;
        }
    }
    oa[row*2] = a0; oa[row*2+1] = a1;
    ob[row*2] = b0; ob[row*2+1] = b1;
}

// ---- count in-degree per dst (both edge types in one launch) ----
__global__ void count_edges(P p) {
    int e = blockIdx.x * 256 + threadIdx.x;
    if (e < NE)            atomicAdd(&p.cnt0[p.ei_u2i[NE + e]], 1);
    else if (e < 2*NE)     atomicAdd(&p.cnt1[p.ei_i2u[NE + (e - NE)]], 1);
}

// ---- two-level exclusive scan of counts -> offsets, cursor ----
__global__ void scan_a(P p) {
    int t = blockIdx.x / NB, j = blockIdx.x % NB;
    const int* cnt = t ? p.cnt1 : p.cnt0;
    int i = j*256 + threadIdx.x;
    int v = (i < N_NODES) ? cnt[i] : 0;
    __shared__ int sd[256];
    sd[threadIdx.x] = v; __syncthreads();
    for (int off = 128; off; off >>= 1) {
        if (threadIdx.x < off) sd[threadIdx.x] += sd[threadIdx.x + off];
        __syncthreads();
    }
    if (threadIdx.x == 0) p.bsum[t*256 + j] = sd[0];
}
__global__ void scan_b(P p) {
    int t = blockIdx.x, tid = threadIdx.x;
    int* bs = p.bsum + t*256;
    int v = (tid < NB) ? bs[tid] : 0;
    __shared__ int sd[256];
    sd[tid] = v; __syncthreads();
    for (int o = 1; o < 256; o <<= 1) {
        int u = (tid >= o) ? sd[tid - o] : 0;
        __syncthreads();
        sd[tid] += u;
        __syncthreads();
    }
    if (tid < NB) bs[tid] = sd[tid] - v;   // exclusive
}
__global__ void scan_c(P p) {
    int t = blockIdx.x / NB, j = blockIdx.x % NB, tid = threadIdx.x;
    const int* cnt = t ? p.cnt1 : p.cnt0;
    int* off = t ? p.off1 : p.off0;
    int* cur = t ? p.cur1 : p.cur0;
    int base = p.bsum[t*256 + j];
    int i = j*256 + tid;
    int v = (i < N_NODES) ? cnt[i] : 0;
    __shared__ int sd[256];
    sd[tid] = v; __syncthreads();
    for (int o = 1; o < 256; o <<= 1) {
        int u = (tid >= o) ? sd[tid - o] : 0;
        __syncthreads();
        sd[tid] += u;
        __syncthreads();
    }
    if (i < N_NODES) { int ex = base + sd[tid] - v; off[i] = ex; cur[i] = ex; }
}

// ---- fill CSR: per edge compute t = exp(leaky_relu(a_s[src]+a_d[dst])) ----
__global__ void fill_edges(P p) {
    int e = blockIdx.x * 256 + threadIdx.x;
    int t, ee;
    if (e < NE)        { t = 0; ee = e; }
    else if (e < 2*NE) { t = 1; ee = e - NE; }
    else return;
    const int*   ei = t ? p.ei_i2u : p.ei_u2i;
    const float* as = t ? p.as1 : p.as0;
    const float* ad = t ? p.ad1 : p.ad0;
    int* cur   = t ? p.cur1 : p.cur0;
    int* srcs  = t ? p.srcs1 : p.srcs0;
    float2* tv = (float2*)(t ? p.tv1 : p.tv0);
    int s = ei[ee], d = ei[NE + ee];
    float l0 = as[s*2]   + ad[d*2];
    float l1 = as[s*2+1] + ad[d*2+1];
    l0 = l0 >= 0.f ? l0 : 0.2f*l0;
    l1 = l1 >= 0.f ? l1 : 0.2f*l1;
    float t0 = __expf(l0), t1 = __expf(l1);
    int pos = atomicAdd(&cur[d], 1);
    srcs[pos] = s;
    tv[pos] = make_float2(t0, t1);
}

// ---- aggregation: one wave per dst, out = (sum t*hs[src]) / (sum t + eps) ----
__global__ __launch_bounds__(256) void aggregate(P p) {
    int t = blockIdx.x >= AGG_B ? 1 : 0;
    int b = blockIdx.x - t*AGG_B;
    int wave = threadIdx.x >> 6, lane = threadIdx.x & 63;
    int d = b*4 + wave;
    const float*  hs   = t ? p.hs1 : p.hs0;
    const int*    srcs = t ? p.srcs1 : p.srcs0;
    const float2* tv   = (const float2*)(t ? p.tv1 : p.tv0);
    const int*    offp = t ? p.off1 : p.off0;
    const int*    cnt  = t ? p.cnt1 : p.cnt0;
    float* out = t ? p.out_user : p.out_item;  // u2i lands on item, i2u on user
    int o = offp[d], n = cnt[d];
    float acc0=0.f, acc1=0.f, z0=0.f, z1=0.f;
    for (int i = 0; i < n; ++i) {
        int s = srcs[o+i];
        float2 tt = tv[o+i];
        const float* h = hs + (size_t)s * 128;
        acc0 += tt.x * h[lane];
        acc1 += tt.y * h[lane + 64];
        z0 += tt.x; z1 += tt.y;
    }
    out[(size_t)d*128 + lane]      = acc0 / (z0 + 1e-16f);
    out[(size_t)d*128 + 64 + lane] = acc1 / (z1 + 1e-16f);
}

// ---- fused bias + LayerNorm + ELU, in place on d_out ----
__global__ __launch_bounds__(256) void ln_elu(P p) {
    int wave = threadIdx.x >> 6, lane = threadIdx.x & 63;
    int r = blockIdx.x*4 + wave;            // 0..99999
    int t = r >= N_NODES ? 1 : 0;
    int row = r - t*N_NODES;
    float* out        = t ? p.out_item : p.out_user;
    const float* bias = t ? p.b_u2i    : p.b_i2u;
    const float* g    = t ? p.ln_g_item : p.ln_g_user;
    const float* bb   = t ? p.ln_b_item : p.ln_b_user;
    float* rowp = out + (size_t)row * 128;
    float h0 = rowp[lane]      + bias[lane];
    float h1 = rowp[lane + 64] + bias[lane + 64];
    float s = h0 + h1;
    for (int o = 1; o < 64; o <<= 1) s += __shfl_xor(s, o);
    float mu = s * (1.f/128.f);
    float d0 = h0 - mu, d1 = h1 - mu;
    float vs = d0*d0 + d1*d1;
    for (int o = 1; o < 64; o <<= 1) vs += __shfl_xor(vs, o);
    float rstd = rsqrtf(vs * (1.f/128.f) + 1e-5f);
    float y0 = d0*rstd*g[lane]      + bb[lane];
    float y1 = d1*rstd*g[lane + 64] + bb[lane + 64];
    y0 = y0 > 0.f ? y0 : expm1f(y0);
    y1 = y1 > 0.f ? y1 : expm1f(y1);
    rowp[lane]      = y0;
    rowp[lane + 64] = y1;
}

static inline char* carve(char*& cur, size_t bytes) {
    char* r = cur;
    cur += (bytes + 255) & ~(size_t)255;
    return r;
}

extern "C" void kernel_launch(void* const* d_in, const int* in_sizes, int n_in,
                              void* d_out, int out_size, void* d_ws, size_t ws_size,
                              hipStream_t stream) {
    P p;
    p.x_user      = (const float*)d_in[0];
    p.x_item      = (const float*)d_in[1];
    p.ei_u2i      = (const int*)d_in[2];
    p.ei_i2u      = (const int*)d_in[3];
    p.w_src_u2i   = (const float*)d_in[4];
    p.w_dst_u2i   = (const float*)d_in[5];
    p.att_src_u2i = (const float*)d_in[6];
    p.att_dst_u2i = (const float*)d_in[7];
    p.b_u2i       = (const float*)d_in[8];
    p.w_src_i2u   = (const float*)d_in[9];
    p.w_dst_i2u   = (const float*)d_in[10];
    p.att_src_i2u = (const float*)d_in[11];
    p.att_dst_i2u = (const float*)d_in[12];
    p.b_i2u       = (const float*)d_in[13];
    p.ln_g_user   = (const float*)d_in[14];
    p.ln_b_user   = (const float*)d_in[15];
    p.ln_g_item   = (const float*)d_in[16];
    p.ln_b_item   = (const float*)d_in[17];

    p.out_user = (float*)d_out;
    p.out_item = (float*)d_out + (size_t)N_NODES * 128;

    char* cur = (char*)d_ws;
    p.hs0  = (float*)carve(cur, (size_t)N_NODES*128*4);
    p.hs1  = (float*)carve(cur, (size_t)N_NODES*128*4);
    p.as0  = (float*)carve(cur, (size_t)N_NODES*2*4);
    p.ad0  = (float*)carve(cur, (size_t)N_NODES*2*4);
    p.as1  = (float*)carve(cur, (size_t)N_NODES*2*4);
    p.ad1  = (float*)carve(cur, (size_t)N_NODES*2*4);
    p.v_s0 = (float*)carve(cur, 256*4);
    p.v_d0 = (float*)carve(cur, 256*4);
    p.v_s1 = (float*)carve(cur, 256*4);
    p.v_d1 = (float*)carve(cur, 256*4);
    int* cnt = (int*)carve(cur, (size_t)2*N_NODES*4);   // cnt0,cnt1 adjacent for one memset
    p.cnt0 = cnt; p.cnt1 = cnt + N_NODES;
    p.off0 = (int*)carve(cur, (size_t)N_NODES*4);
    p.off1 = (int*)carve(cur, (size_t)N_NODES*4);
    p.cur0 = (int*)carve(cur, (size_t)N_NODES*4);
    p.cur1 = (int*)carve(cur, (size_t)N_NODES*4);
    p.bsum = (int*)carve(cur, 2*256*4);
    p.srcs0 = (int*)carve(cur, (size_t)NE*4);
    p.srcs1 = (int*)carve(cur, (size_t)NE*4);
    p.tv0   = (float*)carve(cur, (size_t)NE*8);
    p.tv1   = (float*)carve(cur, (size_t)NE*8);

    hipMemsetAsync(p.cnt0, 0, (size_t)2*N_NODES*4, stream);

    fold_v<<<4, 256, 0, stream>>>(p);
    gemm128<<<(N_NODES + 63)/64, 256, 0, stream>>>(p.x_user, p.w_src_u2i, p.hs0, N_NODES);
    gemm128<<<(N_NODES + 63)/64, 256, 0, stream>>>(p.x_item, p.w_src_i2u, p.hs1, N_NODES);
    skinny<<<2*NB, 256, 0, stream>>>(p);
    count_edges<<<(2*NE + 255)/256, 256, 0, stream>>>(p);
    scan_a<<<2*NB, 256, 0, stream>>>(p);
    scan_b<<<2, 256, 0, stream>>>(p);
    scan_c<<<2*NB, 256, 0, stream>>>(p);
    fill_edges<<<(2*NE + 255)/256, 256, 0, stream>>>(p);
    aggregate<<<2*AGG_B, 256, 0, stream>>>(p);
    ln_elu<<<2*N_NODES/4, 256, 0, stream>>>(p);
}

// Round 2
// 189.521 us; speedup vs baseline: 1.6490x; 1.6490x over previous
//
#include <hip/hip_runtime.h>
#include <hip/hip_bf16.h>

#define N_NODES 50000
#define NE      400000
#define NB      196        // ceil(50000/256)
#define GB      782        // ceil(50000/64)

typedef __attribute__((ext_vector_type(8))) short bf16x8;
typedef __attribute__((ext_vector_type(4))) float f32x4;

static __device__ __forceinline__ unsigned short f2bf(float f) {
    unsigned u = __float_as_uint(f);
    unsigned r = (u + 0x7fffu + ((u >> 16) & 1u)) >> 16;
    return (unsigned short)r;
}

struct P {
    const float *x_user, *x_item;
    const int   *ei_u2i, *ei_i2u;
    const float *w_src_u2i, *w_dst_u2i, *att_src_u2i, *att_dst_u2i, *b_u2i;
    const float *w_src_i2u, *w_dst_i2u, *att_src_i2u, *att_dst_i2u, *b_i2u;
    const float *ln_g_user, *ln_b_user, *ln_g_item, *ln_b_item;
    unsigned short *hs0b, *hs1b;      // bf16 messages [N,128]
    unsigned short *wt0, *wt1;        // bf16 W^T, XOR-swizzled, [128 cols][128 k]
    float *as0, *ad0, *as1, *ad1;     // attn scalars [N,2]
    float *v_s0, *v_d0, *v_s1, *v_d1; // folded att vectors [128][2]
    int   *cnt0, *cnt1, *off0, *off1, *cur0, *cur1;
    int   *bsum;                      // [2*256]
    int   *et0, *et1;                 // 16B tuples {src, t0, t1, pad} per CSR slot
    float *out_user, *out_item;
};

// ---- prep: blocks 0-3 fold v[k,h]; blocks 4-5 build bf16 swizzled W^T ----
__global__ void prep(P p) {
    int b = blockIdx.x, tid = threadIdx.x;
    if (b < 4) {
        const float* w   = b==0? p.w_src_u2i : b==1? p.w_dst_u2i : b==2? p.w_src_i2u : p.w_dst_i2u;
        const float* att = b==0? p.att_src_u2i : b==1? p.att_dst_u2i : b==2? p.att_src_i2u : p.att_dst_i2u;
        float* v         = b==0? p.v_s0 : b==1? p.v_d0 : b==2? p.v_s1 : p.v_d1;
        int k = tid >> 1, h = tid & 1;
        float s = 0.f;
        for (int c = 0; c < 64; ++c) s += w[k*128 + h*64 + c] * att[h*64 + c];
        v[k*2 + h] = s;
    } else {
        const float* w    = (b == 4) ? p.w_src_u2i : p.w_src_i2u;
        unsigned short* wt = (b == 4) ? p.wt0 : p.wt1;
        for (int s = tid; s < 2048; s += 256) {
            int c = s >> 4, g = s & 15;
            int kg = g ^ (c & 7);
            unsigned short u[8];
#pragma unroll
            for (int j = 0; j < 8; ++j) u[j] = f2bf(w[(size_t)(kg*8 + j)*128 + c]);
            uint4 pk;
            pk.x = (unsigned)u[0] | ((unsigned)u[1] << 16);
            pk.y = (unsigned)u[2] | ((unsigned)u[3] << 16);
            pk.z = (unsigned)u[4] | ((unsigned)u[5] << 16);
            pk.w = (unsigned)u[6] | ((unsigned)u[7] << 16);
            *(uint4*)(wt + (size_t)c*128 + g*8) = pk;
        }
    }
}

// ---- MFMA GEMM: hs = bf16(x @ w_src), plus fused a_s/a_d matvecs ----
__global__ __launch_bounds__(256) void gemm(P p) {
    int t   = blockIdx.x >= GB;
    int blk = blockIdx.x - (t ? GB : 0);
    const float* x            = t ? p.x_item : p.x_user;
    const unsigned short* wt  = t ? p.wt1 : p.wt0;
    unsigned short* hs        = t ? p.hs1b : p.hs0b;
    const float2* vsa = (const float2*)(t ? p.v_s1 : p.v_s0);
    const float2* vda = (const float2*)(t ? p.v_d0 : p.v_d1);
    float2* as_out = (float2*)(t ? p.as1 : p.as0);
    float2* ad_out = (float2*)(t ? p.ad0 : p.ad1);

    __shared__ char wlds[32768];
    int tid = threadIdx.x;
#pragma unroll
    for (int it = 0; it < 8; ++it) {
        int off = (tid + it*256) * 16;
        *(uint4*)(wlds + off) = *(const uint4*)((const char*)wt + off);
    }

    int lane = tid & 63, wave = tid >> 6;
    int q = lane >> 4, m = lane & 15;
    int r0 = blk*64 + wave*16;
    int row = r0 + m;
    int rowc = row < N_NODES ? row : N_NODES - 1;
    const float4* xr = (const float4*)(x + (size_t)rowc*128);

    float4 xa[8];
#pragma unroll
    for (int kk = 0; kk < 4; ++kk) {
        xa[kk*2]   = xr[kk*8 + q*2];
        xa[kk*2+1] = xr[kk*8 + q*2 + 1];
    }
    const float* xf = (const float*)xa;

    // fused skinny matvecs (fp32): a_s = x·v_s, a_d = x·v_d
    float as0 = 0.f, as1 = 0.f, ad0 = 0.f, ad1 = 0.f;
#pragma unroll
    for (int kk = 0; kk < 4; ++kk)
#pragma unroll
        for (int jj = 0; jj < 8; ++jj) {
            int k = kk*32 + q*8 + jj;
            float xv = xf[kk*8 + jj];
            float2 vs = vsa[k], vd = vda[k];
            as0 += xv*vs.x; as1 += xv*vs.y;
            ad0 += xv*vd.x; ad1 += xv*vd.y;
        }
#pragma unroll
    for (int o = 16; o < 64; o <<= 1) {
        as0 += __shfl_xor(as0, o); as1 += __shfl_xor(as1, o);
        ad0 += __shfl_xor(ad0, o); ad1 += __shfl_xor(ad1, o);
    }
    if (q == 0 && row < N_NODES) {
        as_out[row] = make_float2(as0, as1);
        ad_out[row] = make_float2(ad0, ad1);
    }

    // bf16 A-fragments
    bf16x8 af[4];
#pragma unroll
    for (int kk = 0; kk < 4; ++kk)
#pragma unroll
        for (int jj = 0; jj < 8; ++jj)
            af[kk][jj] = (short)f2bf(xf[kk*8 + jj]);

    __syncthreads();

    f32x4 acc[8];
#pragma unroll
    for (int cb = 0; cb < 8; ++cb) acc[cb] = (f32x4){0.f, 0.f, 0.f, 0.f};

#pragma unroll
    for (int cb = 0; cb < 8; ++cb) {
        int c = cb*16 + m;
#pragma unroll
        for (int kk = 0; kk < 4; ++kk) {
            int gs = (kk*4 + q) ^ (c & 7);
            bf16x8 bf = *(const bf16x8*)(wlds + (size_t)c*256 + gs*16);
            acc[cb] = __builtin_amdgcn_mfma_f32_16x16x32_bf16(af[kk], bf, acc[cb], 0, 0, 0);
        }
    }

    // store hs as bf16; C/D layout: col = lane&15, row = (lane>>4)*4 + reg
#pragma unroll
    for (int cb = 0; cb < 8; ++cb)
#pragma unroll
        for (int reg = 0; reg < 4; ++reg) {
            int rr = r0 + q*4 + reg;
            if (rr < N_NODES)
                hs[(size_t)rr*128 + cb*16 + m] = f2bf(acc[cb][reg]);
        }
}

// ---- count in-degree per dst ----
__global__ void count_edges(P p) {
    int e = blockIdx.x * 256 + threadIdx.x;
    if (e < NE)            atomicAdd(&p.cnt0[p.ei_u2i[NE + e]], 1);
    else if (e < 2*NE)     atomicAdd(&p.cnt1[p.ei_i2u[NE + (e - NE)]], 1);
}

// ---- two-level exclusive scan ----
__global__ void scan_a(P p) {
    int t = blockIdx.x / NB, j = blockIdx.x % NB;
    const int* cnt = t ? p.cnt1 : p.cnt0;
    int i = j*256 + threadIdx.x;
    int v = (i < N_NODES) ? cnt[i] : 0;
    __shared__ int sd[256];
    sd[threadIdx.x] = v; __syncthreads();
    for (int off = 128; off; off >>= 1) {
        if (threadIdx.x < off) sd[threadIdx.x] += sd[threadIdx.x + off];
        __syncthreads();
    }
    if (threadIdx.x == 0) p.bsum[t*256 + j] = sd[0];
}
__global__ void scan_b(P p) {
    int t = blockIdx.x, tid = threadIdx.x;
    int* bs = p.bsum + t*256;
    int v = (tid < NB) ? bs[tid] : 0;
    __shared__ int sd[256];
    sd[tid] = v; __syncthreads();
    for (int o = 1; o < 256; o <<= 1) {
        int u = (tid >= o) ? sd[tid - o] : 0;
        __syncthreads();
        sd[tid] += u;
        __syncthreads();
    }
    if (tid < NB) bs[tid] = sd[tid] - v;
}
__global__ void scan_c(P p) {
    int t = blockIdx.x / NB, j = blockIdx.x % NB, tid = threadIdx.x;
    const int* cnt = t ? p.cnt1 : p.cnt0;
    int* off = t ? p.off1 : p.off0;
    int* cur = t ? p.cur1 : p.cur0;
    int base = p.bsum[t*256 + j];
    int i = j*256 + tid;
    int v = (i < N_NODES) ? cnt[i] : 0;
    __shared__ int sd[256];
    sd[tid] = v; __syncthreads();
    for (int o = 1; o < 256; o <<= 1) {
        int u = (tid >= o) ? sd[tid - o] : 0;
        __syncthreads();
        sd[tid] += u;
        __syncthreads();
    }
    if (i < N_NODES) { int ex = base + sd[tid] - v; off[i] = ex; cur[i] = ex; }
}

// ---- fill CSR slots with packed {src, t0, t1} tuples ----
__global__ void fill_edges(P p) {
    int e = blockIdx.x * 256 + threadIdx.x;
    int t, ee;
    if (e < NE)        { t = 0; ee = e; }
    else if (e < 2*NE) { t = 1; ee = e - NE; }
    else return;
    const int*   ei = t ? p.ei_i2u : p.ei_u2i;
    const float2* as = (const float2*)(t ? p.as1 : p.as0);
    const float2* ad = (const float2*)(t ? p.ad1 : p.ad0);
    int* cur  = t ? p.cur1 : p.cur0;
    int4* et  = (int4*)(t ? p.et1 : p.et0);
    int s = ei[ee], d = ei[NE + ee];
    float2 a = as[s], b = ad[d];
    float l0 = a.x + b.x, l1 = a.y + b.y;
    l0 = l0 >= 0.f ? l0 : 0.2f*l0;
    l1 = l1 >= 0.f ? l1 : 0.2f*l1;
    int4 v;
    v.x = s;
    v.y = __float_as_int(__expf(l0));
    v.z = __float_as_int(__expf(l1));
    v.w = 0;
    int pos = atomicAdd(&cur[d], 1);
    et[pos] = v;
}

// ---- aggregation + bias + LayerNorm + ELU, one wave per dst ----
__global__ __launch_bounds__(256) void aggregate(P p) {
    int gid = blockIdx.x*4 + (threadIdx.x >> 6);
    int t = gid >= N_NODES;
    int d = gid - (t ? N_NODES : 0);
    int lane = threadIdx.x & 63;
    bool hi = lane >= 32;
    const unsigned* hs = (const unsigned*)(t ? p.hs1b : p.hs0b);
    const int4* et = (const int4*)(t ? p.et1 : p.et0);
    int o = (t ? p.off1 : p.off0)[d];
    int n = (t ? p.cnt1 : p.cnt0)[d];

    float acc0 = 0.f, acc1 = 0.f, z = 0.f;
    int i = 0;
    for (; i + 1 < n; i += 2) {
        int4 e0 = et[o + i];
        int4 e1 = et[o + i + 1];
        unsigned u0 = hs[(size_t)e0.x*64 + lane];
        unsigned u1 = hs[(size_t)e1.x*64 + lane];
        float w0 = __int_as_float(hi ? e0.z : e0.y);
        float w1 = __int_as_float(hi ? e1.z : e1.y);
        acc0 += w0 * __uint_as_float(u0 << 16);
        acc1 += w0 * __uint_as_float(u0 & 0xffff0000u);
        acc0 += w1 * __uint_as_float(u1 << 16);
        acc1 += w1 * __uint_as_float(u1 & 0xffff0000u);
        z += w0 + w1;
    }
    if (i < n) {
        int4 e0 = et[o + i];
        unsigned u0 = hs[(size_t)e0.x*64 + lane];
        float w0 = __int_as_float(hi ? e0.z : e0.y);
        acc0 += w0 * __uint_as_float(u0 << 16);
        acc1 += w0 * __uint_as_float(u0 & 0xffff0000u);
        z += w0;
    }

    float inv = 1.f / (z + 1e-16f);
    const float* bias = t ? p.b_i2u : p.b_u2i;
    const float* lg   = t ? p.ln_g_user : p.ln_g_item;
    const float* lb   = t ? p.ln_b_user : p.ln_b_item;
    float2 bv = ((const float2*)bias)[lane];
    float h0 = acc0*inv + bv.x;
    float h1 = acc1*inv + bv.y;

    float s = h0 + h1;
#pragma unroll
    for (int oo = 1; oo < 64; oo <<= 1) s += __shfl_xor(s, oo);
    float mu = s * (1.f/128.f);
    float d0 = h0 - mu, d1 = h1 - mu;
    float vs = d0*d0 + d1*d1;
#pragma unroll
    for (int oo = 1; oo < 64; oo <<= 1) vs += __shfl_xor(vs, oo);
    float rstd = rsqrtf(vs * (1.f/128.f) + 1e-5f);
    float2 gv = ((const float2*)lg)[lane];
    float2 b2 = ((const float2*)lb)[lane];
    float y0 = d0*rstd*gv.x + b2.x;
    float y1 = d1*rstd*gv.y + b2.y;
    y0 = y0 > 0.f ? y0 : expm1f(y0);
    y1 = y1 > 0.f ? y1 : expm1f(y1);
    float* out = (t ? p.out_user : p.out_item) + (size_t)d*128;
    ((float2*)out)[lane] = make_float2(y0, y1);
}

static inline char* carve(char*& cur, size_t bytes) {
    char* r = cur;
    cur += (bytes + 255) & ~(size_t)255;
    return r;
}

extern "C" void kernel_launch(void* const* d_in, const int* in_sizes, int n_in,
                              void* d_out, int out_size, void* d_ws, size_t ws_size,
                              hipStream_t stream) {
    P p;
    p.x_user      = (const float*)d_in[0];
    p.x_item      = (const float*)d_in[1];
    p.ei_u2i      = (const int*)d_in[2];
    p.ei_i2u      = (const int*)d_in[3];
    p.w_src_u2i   = (const float*)d_in[4];
    p.w_dst_u2i   = (const float*)d_in[5];
    p.att_src_u2i = (const float*)d_in[6];
    p.att_dst_u2i = (const float*)d_in[7];
    p.b_u2i       = (const float*)d_in[8];
    p.w_src_i2u   = (const float*)d_in[9];
    p.w_dst_i2u   = (const float*)d_in[10];
    p.att_src_i2u = (const float*)d_in[11];
    p.att_dst_i2u = (const float*)d_in[12];
    p.b_i2u       = (const float*)d_in[13];
    p.ln_g_user   = (const float*)d_in[14];
    p.ln_b_user   = (const float*)d_in[15];
    p.ln_g_item   = (const float*)d_in[16];
    p.ln_b_item   = (const float*)d_in[17];

    p.out_user = (float*)d_out;
    p.out_item = (float*)d_out + (size_t)N_NODES * 128;

    char* cur = (char*)d_ws;
    p.hs0b = (unsigned short*)carve(cur, (size_t)N_NODES*128*2);
    p.hs1b = (unsigned short*)carve(cur, (size_t)N_NODES*128*2);
    p.wt0  = (unsigned short*)carve(cur, 128*128*2);
    p.wt1  = (unsigned short*)carve(cur, 128*128*2);
    p.as0  = (float*)carve(cur, (size_t)N_NODES*2*4);
    p.ad0  = (float*)carve(cur, (size_t)N_NODES*2*4);
    p.as1  = (float*)carve(cur, (size_t)N_NODES*2*4);
    p.ad1  = (float*)carve(cur, (size_t)N_NODES*2*4);
    p.v_s0 = (float*)carve(cur, 256*4);
    p.v_d0 = (float*)carve(cur, 256*4);
    p.v_s1 = (float*)carve(cur, 256*4);
    p.v_d1 = (float*)carve(cur, 256*4);
    int* cnt = (int*)carve(cur, (size_t)2*N_NODES*4);
    p.cnt0 = cnt; p.cnt1 = cnt + N_NODES;
    p.off0 = (int*)carve(cur, (size_t)N_NODES*4);
    p.off1 = (int*)carve(cur, (size_t)N_NODES*4);
    p.cur0 = (int*)carve(cur, (size_t)N_NODES*4);
    p.cur1 = (int*)carve(cur, (size_t)N_NODES*4);
    p.bsum = (int*)carve(cur, 2*256*4);
    p.et0  = (int*)carve(cur, (size_t)NE*16);
    p.et1  = (int*)carve(cur, (size_t)NE*16);

    hipMemsetAsync(p.cnt0, 0, (size_t)2*N_NODES*4, stream);

    prep<<<6, 256, 0, stream>>>(p);
    count_edges<<<(2*NE + 255)/256, 256, 0, stream>>>(p);
    scan_a<<<2*NB, 256, 0, stream>>>(p);
    scan_b<<<2, 256, 0, stream>>>(p);
    scan_c<<<2*NB, 256, 0, stream>>>(p);
    gemm<<<2*GB, 256, 0, stream>>>(p);
    fill_edges<<<(2*NE + 255)/256, 256, 0, stream>>>(p);
    aggregate<<<(2*N_NODES)/4, 256, 0, stream>>>(p);
}

// Round 4
// 187.667 us; speedup vs baseline: 1.6653x; 1.0099x over previous
//
#include <hip/hip_runtime.h>
#include <hip/hip_bf16.h>

#define N_NODES 50000
#define NE      400000
#define NB      196        // ceil(50000/256)
#define GB      782        // ceil(50000/64)

typedef __attribute__((ext_vector_type(8))) short bf16x8;
typedef __attribute__((ext_vector_type(4))) float f32x4;

static __device__ __forceinline__ unsigned short f2bf(float f) {
    unsigned u = __float_as_uint(f);
    unsigned r = (u + 0x7fffu + ((u >> 16) & 1u)) >> 16;
    return (unsigned short)r;
}

struct P {
    const float *x_user, *x_item;
    const int   *ei_u2i, *ei_i2u;
    const float *w_src_u2i, *w_dst_u2i, *att_src_u2i, *att_dst_u2i, *b_u2i;
    const float *w_src_i2u, *w_dst_i2u, *att_src_i2u, *att_dst_i2u, *b_i2u;
    const float *ln_g_user, *ln_b_user, *ln_g_item, *ln_b_item;
    unsigned short *hs0b, *hs1b;      // bf16 messages [N,128]
    unsigned short *wt0, *wt1;        // bf16 W^T, XOR-swizzled, [128 cols][128 k]
    // naming by EDGE TYPE: as0/ad0 for u2i (as0 idx by user, ad0 idx by item)
    //                      as1/ad1 for i2u (as1 idx by item, ad1 idx by user)
    float *as0, *ad0, *as1, *ad1;
    float *v_s0, *v_d0, *v_s1, *v_d1; // folded att vectors [128][2]
    int   *cnt0, *cnt1, *off0, *off1, *cur0, *cur1;
    int   *bsum;                      // [2*256]
    unsigned short *s0, *s1;          // CSR src indices (u16)
    float *out_user, *out_item;
};

// ---- blocks 0-3: fold v[k,h]; blocks 4-5: bf16 swizzled W^T; rest: count ----
__global__ void prep_count(P p) {
    int b = blockIdx.x, tid = threadIdx.x;
    if (b < 4) {
        const float* w   = b==0? p.w_src_u2i : b==1? p.w_dst_u2i : b==2? p.w_src_i2u : p.w_dst_i2u;
        const float* att = b==0? p.att_src_u2i : b==1? p.att_dst_u2i : b==2? p.att_src_i2u : p.att_dst_i2u;
        float* v         = b==0? p.v_s0 : b==1? p.v_d0 : b==2? p.v_s1 : p.v_d1;
        int k = tid >> 1, h = tid & 1;
        float s = 0.f;
        for (int c = 0; c < 64; ++c) s += w[k*128 + h*64 + c] * att[h*64 + c];
        v[k*2 + h] = s;
    } else if (b < 6) {
        const float* w    = (b == 4) ? p.w_src_u2i : p.w_src_i2u;
        unsigned short* wt = (b == 4) ? p.wt0 : p.wt1;
        for (int s = tid; s < 2048; s += 256) {
            int c = s >> 4, g = s & 15;
            int kg = g ^ (c & 7);
            unsigned short u[8];
#pragma unroll
            for (int j = 0; j < 8; ++j) u[j] = f2bf(w[(size_t)(kg*8 + j)*128 + c]);
            uint4 pk;
            pk.x = (unsigned)u[0] | ((unsigned)u[1] << 16);
            pk.y = (unsigned)u[2] | ((unsigned)u[3] << 16);
            pk.z = (unsigned)u[4] | ((unsigned)u[5] << 16);
            pk.w = (unsigned)u[6] | ((unsigned)u[7] << 16);
            *(uint4*)(wt + (size_t)c*128 + g*8) = pk;
        }
    } else {
        int e = (b - 6) * 256 + tid;
        if (e < NE)            atomicAdd(&p.cnt0[p.ei_u2i[NE + e]], 1);
        else if (e < 2*NE)     atomicAdd(&p.cnt1[p.ei_i2u[NE + (e - NE)]], 1);
    }
}

// ---- MFMA GEMM: hs = bf16(x @ w_src), plus fused a_s/a_d matvecs ----
// t=0: x_user -> hs0 (u2i messages), as0 (u2i a_s), ad1 (i2u a_d)
// t=1: x_item -> hs1 (i2u messages), as1 (i2u a_s), ad0 (u2i a_d)
__global__ __launch_bounds__(256) void gemm(P p) {
    int t   = blockIdx.x >= GB;
    int blk = blockIdx.x - (t ? GB : 0);
    const float* x            = t ? p.x_item : p.x_user;
    const unsigned short* wt  = t ? p.wt1 : p.wt0;
    unsigned short* hs        = t ? p.hs1b : p.hs0b;
    const float2* vsa = (const float2*)(t ? p.v_s1 : p.v_s0);
    const float2* vda = (const float2*)(t ? p.v_d0 : p.v_d1);
    float2* as_out = (float2*)(t ? p.as1 : p.as0);
    float2* ad_out = (float2*)(t ? p.ad0 : p.ad1);

    __shared__ char wlds[32768];
    int tid = threadIdx.x;
#pragma unroll
    for (int it = 0; it < 8; ++it) {
        int off = (tid + it*256) * 16;
        *(uint4*)(wlds + off) = *(const uint4*)((const char*)wt + off);
    }

    int lane = tid & 63, wave = tid >> 6;
    int q = lane >> 4, m = lane & 15;
    int r0 = blk*64 + wave*16;
    int row = r0 + m;
    int rowc = row < N_NODES ? row : N_NODES - 1;
    const float4* xr = (const float4*)(x + (size_t)rowc*128);

    float4 xa[8];
#pragma unroll
    for (int kk = 0; kk < 4; ++kk) {
        xa[kk*2]   = xr[kk*8 + q*2];
        xa[kk*2+1] = xr[kk*8 + q*2 + 1];
    }
    const float* xf = (const float*)xa;

    float as0 = 0.f, as1 = 0.f, ad0 = 0.f, ad1 = 0.f;
#pragma unroll
    for (int kk = 0; kk < 4; ++kk)
#pragma unroll
        for (int jj = 0; jj < 8; ++jj) {
            int k = kk*32 + q*8 + jj;
            float xv = xf[kk*8 + jj];
            float2 vs = vsa[k], vd = vda[k];
            as0 += xv*vs.x; as1 += xv*vs.y;
            ad0 += xv*vd.x; ad1 += xv*vd.y;
        }
#pragma unroll
    for (int o = 16; o < 64; o <<= 1) {
        as0 += __shfl_xor(as0, o); as1 += __shfl_xor(as1, o);
        ad0 += __shfl_xor(ad0, o); ad1 += __shfl_xor(ad1, o);
    }
    if (q == 0 && row < N_NODES) {
        as_out[row] = make_float2(as0, as1);
        ad_out[row] = make_float2(ad0, ad1);
    }

    bf16x8 af[4];
#pragma unroll
    for (int kk = 0; kk < 4; ++kk)
#pragma unroll
        for (int jj = 0; jj < 8; ++jj)
            af[kk][jj] = (short)f2bf(xf[kk*8 + jj]);

    __syncthreads();

    f32x4 acc[8];
#pragma unroll
    for (int cb = 0; cb < 8; ++cb) acc[cb] = (f32x4){0.f, 0.f, 0.f, 0.f};

#pragma unroll
    for (int cb = 0; cb < 8; ++cb) {
        int c = cb*16 + m;
#pragma unroll
        for (int kk = 0; kk < 4; ++kk) {
            int gs = (kk*4 + q) ^ (c & 7);
            bf16x8 bf = *(const bf16x8*)(wlds + (size_t)c*256 + gs*16);
            acc[cb] = __builtin_amdgcn_mfma_f32_16x16x32_bf16(af[kk], bf, acc[cb], 0, 0, 0);
        }
    }

#pragma unroll
    for (int cb = 0; cb < 8; ++cb)
#pragma unroll
        for (int reg = 0; reg < 4; ++reg) {
            int rr = r0 + q*4 + reg;
            if (rr < N_NODES)
                hs[(size_t)rr*128 + cb*16 + m] = f2bf(acc[cb][reg]);
        }
}

// ---- two-level exclusive scan ----
__global__ void scan_a(P p) {
    int t = blockIdx.x / NB, j = blockIdx.x % NB;
    const int* cnt = t ? p.cnt1 : p.cnt0;
    int i = j*256 + threadIdx.x;
    int v = (i < N_NODES) ? cnt[i] : 0;
    __shared__ int sd[256];
    sd[threadIdx.x] = v; __syncthreads();
    for (int off = 128; off; off >>= 1) {
        if (threadIdx.x < off) sd[threadIdx.x] += sd[threadIdx.x + off];
        __syncthreads();
    }
    if (threadIdx.x == 0) p.bsum[t*256 + j] = sd[0];
}
__global__ void scan_b(P p) {
    int t = blockIdx.x, tid = threadIdx.x;
    int* bs = p.bsum + t*256;
    int v = (tid < NB) ? bs[tid] : 0;
    __shared__ int sd[256];
    sd[tid] = v; __syncthreads();
    for (int o = 1; o < 256; o <<= 1) {
        int u = (tid >= o) ? sd[tid - o] : 0;
        __syncthreads();
        sd[tid] += u;
        __syncthreads();
    }
    if (tid < NB) bs[tid] = sd[tid] - v;
}
__global__ void scan_c(P p) {
    int t = blockIdx.x / NB, j = blockIdx.x % NB, tid = threadIdx.x;
    const int* cnt = t ? p.cnt1 : p.cnt0;
    int* off = t ? p.off1 : p.off0;
    int* cur = t ? p.cur1 : p.cur0;
    int base = p.bsum[t*256 + j];
    int i = j*256 + tid;
    int v = (i < N_NODES) ? cnt[i] : 0;
    __shared__ int sd[256];
    sd[tid] = v; __syncthreads();
    for (int o = 1; o < 256; o <<= 1) {
        int u = (tid >= o) ? sd[tid - o] : 0;
        __syncthreads();
        sd[tid] += u;
        __syncthreads();
    }
    if (i < N_NODES) { int ex = base + sd[tid] - v; off[i] = ex; cur[i] = ex; }
}

// ---- fill CSR slots with u16 src indices ----
__global__ void fill_edges(P p) {
    int e = blockIdx.x * 256 + threadIdx.x;
    int t, ee;
    if (e < NE)        { t = 0; ee = e; }
    else if (e < 2*NE) { t = 1; ee = e - NE; }
    else return;
    const int* ei = t ? p.ei_i2u : p.ei_u2i;
    int* cur = t ? p.cur1 : p.cur0;
    unsigned short* srcs = t ? p.s1 : p.s0;
    int s = ei[ee], d = ei[NE + ee];
    int pos = atomicAdd(&cur[d], 1);
    srcs[pos] = (unsigned short)s;
}

// ---- aggregation + softmax-weight recompute + bias + LN + ELU ----
// One wave per dst; 4 x 16-lane groups each handle one edge per iteration.
// t=0: dst=item, edges u2i -> hs0, srcs s0, as0 (user src), ad0 (item dst)
// t=1: dst=user, edges i2u -> hs1, srcs s1, as1 (item src), ad1 (user dst)
__global__ __launch_bounds__(256) void aggregate(P p) {
    int gid = blockIdx.x*4 + (threadIdx.x >> 6);
    int t = gid >= N_NODES;
    int d = gid - (t ? N_NODES : 0);
    int lane = threadIdx.x & 63;
    int g = lane >> 4;       // edge subgroup 0..3
    int m = lane & 15;       // column lane: cols 8m..8m+7
    int headhi = m >> 3;     // 0: cols<64 (head0), 1: head1

    const unsigned short* hs   = t ? p.hs1b : p.hs0b;
    const unsigned short* srcs = t ? p.s1 : p.s0;
    const float2* as2 = (const float2*)(t ? p.as1 : p.as0);
    const float2* ad2 = (const float2*)(t ? p.ad1 : p.ad0);   // FIXED: edge-type naming
    int o = (t ? p.off1 : p.off0)[d];
    int n = (t ? p.cnt1 : p.cnt0)[d];

    float2 adv = ad2[d];
    float adh = headhi ? adv.y : adv.x;

    float acc[8];
#pragma unroll
    for (int j = 0; j < 8; ++j) acc[j] = 0.f;
    float z = 0.f;

    int nit = (n + 3) >> 2;
    for (int i = 0; i < nit; ++i) {
        int ei = i*4 + g;
        bool act = ei < n;
        int s = srcs[o + (act ? ei : 0)];
        float2 a = as2[s];
        float l = (headhi ? a.y : a.x) + adh;
        l = l >= 0.f ? l : 0.2f*l;
        float w = act ? __expf(l) : 0.f;
        uint4 q = *(const uint4*)(hs + (size_t)s*128 + m*8);
        unsigned uu[4] = {q.x, q.y, q.z, q.w};
#pragma unroll
        for (int j = 0; j < 4; ++j) {
            acc[2*j]   += w * __uint_as_float(uu[j] << 16);
            acc[2*j+1] += w * __uint_as_float(uu[j] & 0xffff0000u);
        }
        z += w;
    }

    // reduce across the 4 groups
#pragma unroll
    for (int off = 16; off < 64; off <<= 1) {
#pragma unroll
        for (int j = 0; j < 8; ++j) acc[j] += __shfl_xor(acc[j], off);
        z += __shfl_xor(z, off);
    }

    float inv = 1.f / (z + 1e-16f);
    const float* bias = t ? p.b_i2u : p.b_u2i;
    const float* lg   = t ? p.ln_g_user : p.ln_g_item;
    const float* lb   = t ? p.ln_b_user : p.ln_b_item;
    float4 bv0 = *(const float4*)(bias + m*8);
    float4 bv1 = *(const float4*)(bias + m*8 + 4);
    float bvv[8] = {bv0.x,bv0.y,bv0.z,bv0.w,bv1.x,bv1.y,bv1.z,bv1.w};
    float h[8];
#pragma unroll
    for (int j = 0; j < 8; ++j) h[j] = acc[j]*inv + bvv[j];

    float s8 = 0.f;
#pragma unroll
    for (int j = 0; j < 8; ++j) s8 += h[j];
#pragma unroll
    for (int off = 1; off < 16; off <<= 1) s8 += __shfl_xor(s8, off);
    float mu = s8 * (1.f/128.f);
    float vs = 0.f;
#pragma unroll
    for (int j = 0; j < 8; ++j) { h[j] -= mu; vs += h[j]*h[j]; }
#pragma unroll
    for (int off = 1; off < 16; off <<= 1) vs += __shfl_xor(vs, off);
    float rstd = rsqrtf(vs * (1.f/128.f) + 1e-5f);

    if (g == 0) {
        float4 gv0 = *(const float4*)(lg + m*8);
        float4 gv1 = *(const float4*)(lg + m*8 + 4);
        float4 lb0 = *(const float4*)(lb + m*8);
        float4 lb1 = *(const float4*)(lb + m*8 + 4);
        float gvv[8] = {gv0.x,gv0.y,gv0.z,gv0.w,gv1.x,gv1.y,gv1.z,gv1.w};
        float lbb[8] = {lb0.x,lb0.y,lb0.z,lb0.w,lb1.x,lb1.y,lb1.z,lb1.w};
        float y[8];
#pragma unroll
        for (int j = 0; j < 8; ++j) {
            float v = h[j]*rstd*gvv[j] + lbb[j];
            y[j] = v > 0.f ? v : expm1f(v);
        }
        float* out = (t ? p.out_user : p.out_item) + (size_t)d*128 + m*8;
        *(float4*)out       = make_float4(y[0],y[1],y[2],y[3]);
        *(float4*)(out + 4) = make_float4(y[4],y[5],y[6],y[7]);
    }
}

static inline char* carve(char*& cur, size_t bytes) {
    char* r = cur;
    cur += (bytes + 255) & ~(size_t)255;
    return r;
}

extern "C" void kernel_launch(void* const* d_in, const int* in_sizes, int n_in,
                              void* d_out, int out_size, void* d_ws, size_t ws_size,
                              hipStream_t stream) {
    P p;
    p.x_user      = (const float*)d_in[0];
    p.x_item      = (const float*)d_in[1];
    p.ei_u2i      = (const int*)d_in[2];
    p.ei_i2u      = (const int*)d_in[3];
    p.w_src_u2i   = (const float*)d_in[4];
    p.w_dst_u2i   = (const float*)d_in[5];
    p.att_src_u2i = (const float*)d_in[6];
    p.att_dst_u2i = (const float*)d_in[7];
    p.b_u2i       = (const float*)d_in[8];
    p.w_src_i2u   = (const float*)d_in[9];
    p.w_dst_i2u   = (const float*)d_in[10];
    p.att_src_i2u = (const float*)d_in[11];
    p.att_dst_i2u = (const float*)d_in[12];
    p.b_i2u       = (const float*)d_in[13];
    p.ln_g_user   = (const float*)d_in[14];
    p.ln_b_user   = (const float*)d_in[15];
    p.ln_g_item   = (const float*)d_in[16];
    p.ln_b_item   = (const float*)d_in[17];

    p.out_user = (float*)d_out;
    p.out_item = (float*)d_out + (size_t)N_NODES * 128;

    char* cur = (char*)d_ws;
    p.hs0b = (unsigned short*)carve(cur, (size_t)N_NODES*128*2);
    p.hs1b = (unsigned short*)carve(cur, (size_t)N_NODES*128*2);
    p.wt0  = (unsigned short*)carve(cur, 128*128*2);
    p.wt1  = (unsigned short*)carve(cur, 128*128*2);
    p.as0  = (float*)carve(cur, (size_t)N_NODES*2*4);
    p.ad0  = (float*)carve(cur, (size_t)N_NODES*2*4);
    p.as1  = (float*)carve(cur, (size_t)N_NODES*2*4);
    p.ad1  = (float*)carve(cur, (size_t)N_NODES*2*4);
    p.v_s0 = (float*)carve(cur, 256*4);
    p.v_d0 = (float*)carve(cur, 256*4);
    p.v_s1 = (float*)carve(cur, 256*4);
    p.v_d1 = (float*)carve(cur, 256*4);
    int* cnt = (int*)carve(cur, (size_t)2*N_NODES*4);
    p.cnt0 = cnt; p.cnt1 = cnt + N_NODES;
    p.off0 = (int*)carve(cur, (size_t)N_NODES*4);
    p.off1 = (int*)carve(cur, (size_t)N_NODES*4);
    p.cur0 = (int*)carve(cur, (size_t)N_NODES*4);
    p.cur1 = (int*)carve(cur, (size_t)N_NODES*4);
    p.bsum = (int*)carve(cur, 2*256*4);
    p.s0   = (unsigned short*)carve(cur, (size_t)NE*2);
    p.s1   = (unsigned short*)carve(cur, (size_t)NE*2);

    hipMemsetAsync(p.cnt0, 0, (size_t)2*N_NODES*4, stream);

    prep_count<<<6 + (2*NE + 255)/256, 256, 0, stream>>>(p);
    scan_a<<<2*NB, 256, 0, stream>>>(p);
    scan_b<<<2, 256, 0, stream>>>(p);
    scan_c<<<2*NB, 256, 0, stream>>>(p);
    fill_edges<<<(2*NE + 255)/256, 256, 0, stream>>>(p);
    gemm<<<2*GB, 256, 0, stream>>>(p);
    aggregate<<<(2*N_NODES)/4, 256, 0, stream>>>(p);
}

// Round 5
// 182.571 us; speedup vs baseline: 1.7117x; 1.0279x over previous
//
#include <hip/hip_runtime.h>
#include <hip/hip_bf16.h>

#define N_NODES 50000
#define NE      400000
#define NB      196        // ceil(50000/256)
#define GB      782        // ceil(50000/64)

typedef __attribute__((ext_vector_type(8))) short bf16x8;
typedef __attribute__((ext_vector_type(4))) float f32x4;

static __device__ __forceinline__ unsigned short f2bf(float f) {
    unsigned u = __float_as_uint(f);
    unsigned r = (u + 0x7fffu + ((u >> 16) & 1u)) >> 16;
    return (unsigned short)r;
}

struct P {
    const float *x_user, *x_item;
    const int   *ei_u2i, *ei_i2u;
    const float *w_src_u2i, *w_dst_u2i, *att_src_u2i, *att_dst_u2i, *b_u2i;
    const float *w_src_i2u, *w_dst_i2u, *att_src_i2u, *att_dst_i2u, *b_i2u;
    const float *ln_g_user, *ln_b_user, *ln_g_item, *ln_b_item;
    unsigned short *hs0b, *hs1b;      // bf16 messages [N,128]
    unsigned short *wt0, *wt1;        // bf16 W^T, XOR-swizzled, [128 cols][128 k]
    // naming by EDGE TYPE: as0/ad0 for u2i (as0 idx by user, ad0 idx by item)
    //                      as1/ad1 for i2u (as1 idx by item, ad1 idx by user)
    float *as0, *ad0, *as1, *ad1;
    float *v_s0, *v_d0, *v_s1, *v_d1; // folded att vectors [128][2]
    int   *cnt0, *cnt1, *off0, *off1, *cur0, *cur1;
    int   *bsum;                      // [2*256]
    int   *et0, *et1;                 // 16B tuples {src, w0, w1, 0} per CSR slot
    float *out_user, *out_item;
};

// ---- blocks 0-3: fold v[k,h]; blocks 4-5: bf16 swizzled W^T; rest: count ----
__global__ void prep_count(P p) {
    int b = blockIdx.x, tid = threadIdx.x;
    if (b < 4) {
        const float* w   = b==0? p.w_src_u2i : b==1? p.w_dst_u2i : b==2? p.w_src_i2u : p.w_dst_i2u;
        const float* att = b==0? p.att_src_u2i : b==1? p.att_dst_u2i : b==2? p.att_src_i2u : p.att_dst_i2u;
        float* v         = b==0? p.v_s0 : b==1? p.v_d0 : b==2? p.v_s1 : p.v_d1;
        int k = tid >> 1, h = tid & 1;
        float s = 0.f;
        for (int c = 0; c < 64; ++c) s += w[k*128 + h*64 + c] * att[h*64 + c];
        v[k*2 + h] = s;
    } else if (b < 6) {
        const float* w    = (b == 4) ? p.w_src_u2i : p.w_src_i2u;
        unsigned short* wt = (b == 4) ? p.wt0 : p.wt1;
        for (int s = tid; s < 2048; s += 256) {
            int c = s >> 4, g = s & 15;
            int kg = g ^ (c & 7);
            unsigned short u[8];
#pragma unroll
            for (int j = 0; j < 8; ++j) u[j] = f2bf(w[(size_t)(kg*8 + j)*128 + c]);
            uint4 pk;
            pk.x = (unsigned)u[0] | ((unsigned)u[1] << 16);
            pk.y = (unsigned)u[2] | ((unsigned)u[3] << 16);
            pk.z = (unsigned)u[4] | ((unsigned)u[5] << 16);
            pk.w = (unsigned)u[6] | ((unsigned)u[7] << 16);
            *(uint4*)(wt + (size_t)c*128 + g*8) = pk;
        }
    } else {
        int e = (b - 6) * 256 + tid;
        if (e < NE)            atomicAdd(&p.cnt0[p.ei_u2i[NE + e]], 1);
        else if (e < 2*NE)     atomicAdd(&p.cnt1[p.ei_i2u[NE + (e - NE)]], 1);
    }
}

// ---- MFMA GEMM: hs = bf16(x @ w_src), plus fused a_s/a_d matvecs ----
// t=0: x_user -> hs0 (u2i messages), as0 (u2i a_s), ad1 (i2u a_d)
// t=1: x_item -> hs1 (i2u messages), as1 (i2u a_s), ad0 (u2i a_d)
__global__ __launch_bounds__(256) void gemm(P p) {
    int t   = blockIdx.x >= GB;
    int blk = blockIdx.x - (t ? GB : 0);
    const float* x            = t ? p.x_item : p.x_user;
    const unsigned short* wt  = t ? p.wt1 : p.wt0;
    unsigned short* hs        = t ? p.hs1b : p.hs0b;
    const float2* vsa = (const float2*)(t ? p.v_s1 : p.v_s0);
    const float2* vda = (const float2*)(t ? p.v_d0 : p.v_d1);
    float2* as_out = (float2*)(t ? p.as1 : p.as0);
    float2* ad_out = (float2*)(t ? p.ad0 : p.ad1);

    __shared__ char wlds[32768];
    int tid = threadIdx.x;
#pragma unroll
    for (int it = 0; it < 8; ++it) {
        int off = (tid + it*256) * 16;
        *(uint4*)(wlds + off) = *(const uint4*)((const char*)wt + off);
    }

    int lane = tid & 63, wave = tid >> 6;
    int q = lane >> 4, m = lane & 15;
    int r0 = blk*64 + wave*16;
    int row = r0 + m;
    int rowc = row < N_NODES ? row : N_NODES - 1;
    const float4* xr = (const float4*)(x + (size_t)rowc*128);

    float4 xa[8];
#pragma unroll
    for (int kk = 0; kk < 4; ++kk) {
        xa[kk*2]   = xr[kk*8 + q*2];
        xa[kk*2+1] = xr[kk*8 + q*2 + 1];
    }
    const float* xf = (const float*)xa;

    float as0 = 0.f, as1 = 0.f, ad0 = 0.f, ad1 = 0.f;
#pragma unroll
    for (int kk = 0; kk < 4; ++kk)
#pragma unroll
        for (int jj = 0; jj < 8; ++jj) {
            int k = kk*32 + q*8 + jj;
            float xv = xf[kk*8 + jj];
            float2 vs = vsa[k], vd = vda[k];
            as0 += xv*vs.x; as1 += xv*vs.y;
            ad0 += xv*vd.x; ad1 += xv*vd.y;
        }
#pragma unroll
    for (int o = 16; o < 64; o <<= 1) {
        as0 += __shfl_xor(as0, o); as1 += __shfl_xor(as1, o);
        ad0 += __shfl_xor(ad0, o); ad1 += __shfl_xor(ad1, o);
    }
    if (q == 0 && row < N_NODES) {
        as_out[row] = make_float2(as0, as1);
        ad_out[row] = make_float2(ad0, ad1);
    }

    bf16x8 af[4];
#pragma unroll
    for (int kk = 0; kk < 4; ++kk)
#pragma unroll
        for (int jj = 0; jj < 8; ++jj)
            af[kk][jj] = (short)f2bf(xf[kk*8 + jj]);

    __syncthreads();

    f32x4 acc[8];
#pragma unroll
    for (int cb = 0; cb < 8; ++cb) acc[cb] = (f32x4){0.f, 0.f, 0.f, 0.f};

#pragma unroll
    for (int cb = 0; cb < 8; ++cb) {
        int c = cb*16 + m;
#pragma unroll
        for (int kk = 0; kk < 4; ++kk) {
            int gs = (kk*4 + q) ^ (c & 7);
            bf16x8 bf = *(const bf16x8*)(wlds + (size_t)c*256 + gs*16);
            acc[cb] = __builtin_amdgcn_mfma_f32_16x16x32_bf16(af[kk], bf, acc[cb], 0, 0, 0);
        }
    }

#pragma unroll
    for (int cb = 0; cb < 8; ++cb)
#pragma unroll
        for (int reg = 0; reg < 4; ++reg) {
            int rr = r0 + q*4 + reg;
            if (rr < N_NODES)
                hs[(size_t)rr*128 + cb*16 + m] = f2bf(acc[cb][reg]);
        }
}

// ---- per-block partial sums of counts ----
__global__ void scan_a(P p) {
    int t = blockIdx.x / NB, j = blockIdx.x % NB;
    const int* cnt = t ? p.cnt1 : p.cnt0;
    int i = j*256 + threadIdx.x;
    int v = (i < N_NODES) ? cnt[i] : 0;
    __shared__ int sd[256];
    sd[threadIdx.x] = v; __syncthreads();
    for (int off = 128; off; off >>= 1) {
        if (threadIdx.x < off) sd[threadIdx.x] += sd[threadIdx.x + off];
        __syncthreads();
    }
    if (threadIdx.x == 0) p.bsum[t*256 + j] = sd[0];
}

// ---- merged: block-prefix of bsum (redundant per block) + per-elem scan ----
__global__ void scan_c(P p) {
    int t = blockIdx.x / NB, j = blockIdx.x % NB, tid = threadIdx.x;
    const int* cnt = t ? p.cnt1 : p.cnt0;
    int* off = t ? p.off1 : p.off0;
    int* cur = t ? p.cur1 : p.cur0;

    __shared__ int sb[256];
    int bv = (tid < NB) ? p.bsum[t*256 + tid] : 0;
    sb[tid] = bv; __syncthreads();
    for (int o = 1; o < 256; o <<= 1) {
        int u = (tid >= o) ? sb[tid - o] : 0;
        __syncthreads();
        sb[tid] += u;
        __syncthreads();
    }
    int base = (j > 0) ? sb[j-1] : 0;

    int i = j*256 + tid;
    int v = (i < N_NODES) ? cnt[i] : 0;
    __shared__ int sd[256];
    sd[tid] = v; __syncthreads();
    for (int o = 1; o < 256; o <<= 1) {
        int u = (tid >= o) ? sd[tid - o] : 0;
        __syncthreads();
        sd[tid] += u;
        __syncthreads();
    }
    if (i < N_NODES) { int ex = base + sd[tid] - v; off[i] = ex; cur[i] = ex; }
}

// ---- fill CSR slots: tuple {src, w0, w1, 0}, w = exp(leakyrelu(a_s+a_d)) ----
__global__ void fill_edges(P p) {
    int e = blockIdx.x * 256 + threadIdx.x;
    int t, ee;
    if (e < NE)        { t = 0; ee = e; }
    else if (e < 2*NE) { t = 1; ee = e - NE; }
    else return;
    const int* ei = t ? p.ei_i2u : p.ei_u2i;
    const float2* as2 = (const float2*)(t ? p.as1 : p.as0);
    const float2* ad2 = (const float2*)(t ? p.ad1 : p.ad0);
    int* cur = t ? p.cur1 : p.cur0;
    int4* et = (int4*)(t ? p.et1 : p.et0);
    int s = ei[ee], d = ei[NE + ee];
    float2 a = as2[s], b = ad2[d];
    float l0 = a.x + b.x, l1 = a.y + b.y;
    l0 = l0 >= 0.f ? l0 : 0.2f*l0;
    l1 = l1 >= 0.f ? l1 : 0.2f*l1;
    int4 v;
    v.x = s;
    v.y = __float_as_int(__expf(l0));
    v.z = __float_as_int(__expf(l1));
    v.w = 0;
    int pos = atomicAdd(&cur[d], 1);
    et[pos] = v;
}

// ---- aggregation + bias + LN + ELU ----
// One wave per dst; 4 x 16-lane groups each handle one edge per iteration.
// Weights precomputed in tuples (2-deep load chain, no exp in loop).
__global__ __launch_bounds__(256) void aggregate(P p) {
    int gid = blockIdx.x*4 + (threadIdx.x >> 6);
    int t = gid >= N_NODES;
    int d = gid - (t ? N_NODES : 0);
    int lane = threadIdx.x & 63;
    int g = lane >> 4;       // edge subgroup 0..3
    int m = lane & 15;       // column lane: cols 8m..8m+7
    int headhi = m >> 3;     // 0: head0 (cols<64), 1: head1
    unsigned mo = (unsigned)m * 16;   // byte offset within hs row

    const char* hs = (const char*)(t ? p.hs1b : p.hs0b);
    const int4* et = (const int4*)(t ? p.et1 : p.et0);
    int o = (t ? p.off1 : p.off0)[d];
    int n = (t ? p.cnt1 : p.cnt0)[d];

    float acc[8];
#pragma unroll
    for (int j = 0; j < 8; ++j) acc[j] = 0.f;
    float z = 0.f;

    int nit = (n + 3) >> 2;
    for (int i = 0; i < nit; ++i) {
        int ei4 = i*4 + g;
        bool act = ei4 < n;
        int4 e = et[o + (act ? ei4 : 0)];
        float w = act ? __int_as_float(headhi ? e.z : e.y) : 0.f;
        uint4 q = *(const uint4*)(hs + (((unsigned)e.x << 8) + mo));
        unsigned uu[4] = {q.x, q.y, q.z, q.w};
#pragma unroll
        for (int j = 0; j < 4; ++j) {
            acc[2*j]   += w * __uint_as_float(uu[j] << 16);
            acc[2*j+1] += w * __uint_as_float(uu[j] & 0xffff0000u);
        }
        z += w;
    }

    // reduce across the 4 groups (keeps m, i.e. keeps column & head)
#pragma unroll
    for (int off = 16; off < 64; off <<= 1) {
#pragma unroll
        for (int j = 0; j < 8; ++j) acc[j] += __shfl_xor(acc[j], off);
        z += __shfl_xor(z, off);
    }

    float inv = 1.f / (z + 1e-16f);
    const float* bias = t ? p.b_i2u : p.b_u2i;
    const float* lg   = t ? p.ln_g_user : p.ln_g_item;
    const float* lb   = t ? p.ln_b_user : p.ln_b_item;
    float4 bv0 = *(const float4*)(bias + m*8);
    float4 bv1 = *(const float4*)(bias + m*8 + 4);
    float bvv[8] = {bv0.x,bv0.y,bv0.z,bv0.w,bv1.x,bv1.y,bv1.z,bv1.w};
    float h[8];
#pragma unroll
    for (int j = 0; j < 8; ++j) h[j] = acc[j]*inv + bvv[j];

    float s8 = 0.f;
#pragma unroll
    for (int j = 0; j < 8; ++j) s8 += h[j];
#pragma unroll
    for (int off = 1; off < 16; off <<= 1) s8 += __shfl_xor(s8, off);
    float mu = s8 * (1.f/128.f);
    float vs = 0.f;
#pragma unroll
    for (int j = 0; j < 8; ++j) { h[j] -= mu; vs += h[j]*h[j]; }
#pragma unroll
    for (int off = 1; off < 16; off <<= 1) vs += __shfl_xor(vs, off);
    float rstd = rsqrtf(vs * (1.f/128.f) + 1e-5f);

    if (g == 0) {
        float4 gv0 = *(const float4*)(lg + m*8);
        float4 gv1 = *(const float4*)(lg + m*8 + 4);
        float4 lb0 = *(const float4*)(lb + m*8);
        float4 lb1 = *(const float4*)(lb + m*8 + 4);
        float gvv[8] = {gv0.x,gv0.y,gv0.z,gv0.w,gv1.x,gv1.y,gv1.z,gv1.w};
        float lbb[8] = {lb0.x,lb0.y,lb0.z,lb0.w,lb1.x,lb1.y,lb1.z,lb1.w};
        float y[8];
#pragma unroll
        for (int j = 0; j < 8; ++j) {
            float v = h[j]*rstd*gvv[j] + lbb[j];
            y[j] = v > 0.f ? v : expm1f(v);
        }
        float* out = (t ? p.out_user : p.out_item) + (size_t)d*128 + m*8;
        *(float4*)out       = make_float4(y[0],y[1],y[2],y[3]);
        *(float4*)(out + 4) = make_float4(y[4],y[5],y[6],y[7]);
    }
}

static inline char* carve(char*& cur, size_t bytes) {
    char* r = cur;
    cur += (bytes + 255) & ~(size_t)255;
    return r;
}

extern "C" void kernel_launch(void* const* d_in, const int* in_sizes, int n_in,
                              void* d_out, int out_size, void* d_ws, size_t ws_size,
                              hipStream_t stream) {
    P p;
    p.x_user      = (const float*)d_in[0];
    p.x_item      = (const float*)d_in[1];
    p.ei_u2i      = (const int*)d_in[2];
    p.ei_i2u      = (const int*)d_in[3];
    p.w_src_u2i   = (const float*)d_in[4];
    p.w_dst_u2i   = (const float*)d_in[5];
    p.att_src_u2i = (const float*)d_in[6];
    p.att_dst_u2i = (const float*)d_in[7];
    p.b_u2i       = (const float*)d_in[8];
    p.w_src_i2u   = (const float*)d_in[9];
    p.w_dst_i2u   = (const float*)d_in[10];
    p.att_src_i2u = (const float*)d_in[11];
    p.att_dst_i2u = (const float*)d_in[12];
    p.b_i2u       = (const float*)d_in[13];
    p.ln_g_user   = (const float*)d_in[14];
    p.ln_b_user   = (const float*)d_in[15];
    p.ln_g_item   = (const float*)d_in[16];
    p.ln_b_item   = (const float*)d_in[17];

    p.out_user = (float*)d_out;
    p.out_item = (float*)d_out + (size_t)N_NODES * 128;

    char* cur = (char*)d_ws;
    p.hs0b = (unsigned short*)carve(cur, (size_t)N_NODES*128*2);
    p.hs1b = (unsigned short*)carve(cur, (size_t)N_NODES*128*2);
    p.wt0  = (unsigned short*)carve(cur, 128*128*2);
    p.wt1  = (unsigned short*)carve(cur, 128*128*2);
    p.as0  = (float*)carve(cur, (size_t)N_NODES*2*4);
    p.ad0  = (float*)carve(cur, (size_t)N_NODES*2*4);
    p.as1  = (float*)carve(cur, (size_t)N_NODES*2*4);
    p.ad1  = (float*)carve(cur, (size_t)N_NODES*2*4);
    p.v_s0 = (float*)carve(cur, 256*4);
    p.v_d0 = (float*)carve(cur, 256*4);
    p.v_s1 = (float*)carve(cur, 256*4);
    p.v_d1 = (float*)carve(cur, 256*4);
    int* cnt = (int*)carve(cur, (size_t)2*N_NODES*4);
    p.cnt0 = cnt; p.cnt1 = cnt + N_NODES;
    p.off0 = (int*)carve(cur, (size_t)N_NODES*4);
    p.off1 = (int*)carve(cur, (size_t)N_NODES*4);
    p.cur0 = (int*)carve(cur, (size_t)N_NODES*4);
    p.cur1 = (int*)carve(cur, (size_t)N_NODES*4);
    p.bsum = (int*)carve(cur, 2*256*4);
    p.et0  = (int*)carve(cur, (size_t)NE*16);
    p.et1  = (int*)carve(cur, (size_t)NE*16);

    hipMemsetAsync(p.cnt0, 0, (size_t)2*N_NODES*4, stream);

    prep_count<<<6 + (2*NE + 255)/256, 256, 0, stream>>>(p);
    scan_a<<<2*NB, 256, 0, stream>>>(p);
    scan_c<<<2*NB, 256, 0, stream>>>(p);
    gemm<<<2*GB, 256, 0, stream>>>(p);
    fill_edges<<<(2*NE + 255)/256, 256, 0, stream>>>(p);
    aggregate<<<(2*N_NODES)/4, 256, 0, stream>>>(p);
}

// Round 6
// 162.957 us; speedup vs baseline: 1.9178x; 1.1204x over previous
//
#include <hip/hip_runtime.h>
#include <hip/hip_bf16.h>

#define N_NODES 50000
#define NE      400000
#define NB      196        // ceil(50000/256)
#define GB      782        // ceil(50000/64)

typedef __attribute__((ext_vector_type(8))) short bf16x8;
typedef __attribute__((ext_vector_type(4))) float f32x4;

static __device__ __forceinline__ unsigned short f2bf(float f) {
    unsigned u = __float_as_uint(f);
    unsigned r = (u + 0x7fffu + ((u >> 16) & 1u)) >> 16;
    return (unsigned short)r;
}

struct P {
    const float *x_user, *x_item;
    const int   *ei_u2i, *ei_i2u;
    const float *w_src_u2i, *w_dst_u2i, *att_src_u2i, *att_dst_u2i, *b_u2i;
    const float *w_src_i2u, *w_dst_i2u, *att_src_i2u, *att_dst_i2u, *b_i2u;
    const float *ln_g_user, *ln_b_user, *ln_g_item, *ln_b_item;
    unsigned short *hs0b, *hs1b;      // bf16 messages [N,128]
    unsigned short *wt0, *wt1;        // bf16 W^T, XOR-swizzled, [128 cols][128 k]
    // naming by EDGE TYPE: as0/ad0 for u2i (as0 idx by user, ad0 idx by item)
    //                      as1/ad1 for i2u (as1 idx by item, ad1 idx by user)
    float *as0, *ad0, *as1, *ad1;
    float *v_s0, *v_d0, *v_s1, *v_d1; // folded att vectors [128][2]
    int   *cnt0, *cnt1, *off0, *off1, *cur0, *cur1;
    int   *bsum;                      // [2*256]
    int   *et0, *et1;                 // 16B tuples {src, w0, w1, 0} per CSR slot
    float *out_user, *out_item;
};

// ---- blocks 0-3: fold v[k,h]; blocks 4-5: bf16 swizzled W^T; rest: count ----
__global__ void prep_count(P p) {
    int b = blockIdx.x, tid = threadIdx.x;
    if (b < 4) {
        const float* w   = b==0? p.w_src_u2i : b==1? p.w_dst_u2i : b==2? p.w_src_i2u : p.w_dst_i2u;
        const float* att = b==0? p.att_src_u2i : b==1? p.att_dst_u2i : b==2? p.att_src_i2u : p.att_dst_i2u;
        float* v         = b==0? p.v_s0 : b==1? p.v_d0 : b==2? p.v_s1 : p.v_d1;
        int k = tid >> 1, h = tid & 1;
        float s = 0.f;
        for (int c = 0; c < 64; ++c) s += w[k*128 + h*64 + c] * att[h*64 + c];
        v[k*2 + h] = s;
    } else if (b < 6) {
        const float* w    = (b == 4) ? p.w_src_u2i : p.w_src_i2u;
        unsigned short* wt = (b == 4) ? p.wt0 : p.wt1;
        for (int s = tid; s < 2048; s += 256) {
            int c = s >> 4, g = s & 15;
            int kg = g ^ (c & 7);
            unsigned short u[8];
#pragma unroll
            for (int j = 0; j < 8; ++j) u[j] = f2bf(w[(size_t)(kg*8 + j)*128 + c]);
            uint4 pk;
            pk.x = (unsigned)u[0] | ((unsigned)u[1] << 16);
            pk.y = (unsigned)u[2] | ((unsigned)u[3] << 16);
            pk.z = (unsigned)u[4] | ((unsigned)u[5] << 16);
            pk.w = (unsigned)u[6] | ((unsigned)u[7] << 16);
            *(uint4*)(wt + (size_t)c*128 + g*8) = pk;
        }
    } else {
        int e = (b - 6) * 256 + tid;
        if (e < NE)            atomicAdd(&p.cnt0[p.ei_u2i[NE + e]], 1);
        else if (e < 2*NE)     atomicAdd(&p.cnt1[p.ei_i2u[NE + (e - NE)]], 1);
    }
}

// ---- MFMA GEMM: hs = bf16(x @ w_src), plus fused a_s/a_d matvecs ----
// t=0: x_user -> hs0 (u2i messages), as0 (u2i a_s), ad1 (i2u a_d)
// t=1: x_item -> hs1 (i2u messages), as1 (i2u a_s), ad0 (u2i a_d)
__global__ __launch_bounds__(256) void gemm(P p) {
    int t   = blockIdx.x >= GB;
    int blk = blockIdx.x - (t ? GB : 0);
    const float* x            = t ? p.x_item : p.x_user;
    const unsigned short* wt  = t ? p.wt1 : p.wt0;
    unsigned short* hs        = t ? p.hs1b : p.hs0b;
    const float2* vsa = (const float2*)(t ? p.v_s1 : p.v_s0);
    const float2* vda = (const float2*)(t ? p.v_d0 : p.v_d1);
    float2* as_out = (float2*)(t ? p.as1 : p.as0);
    float2* ad_out = (float2*)(t ? p.ad0 : p.ad1);

    __shared__ char wlds[32768];
    int tid = threadIdx.x;
#pragma unroll
    for (int it = 0; it < 8; ++it) {
        int off = (tid + it*256) * 16;
        *(uint4*)(wlds + off) = *(const uint4*)((const char*)wt + off);
    }

    int lane = tid & 63, wave = tid >> 6;
    int q = lane >> 4, m = lane & 15;
    int r0 = blk*64 + wave*16;
    int row = r0 + m;
    int rowc = row < N_NODES ? row : N_NODES - 1;
    const float4* xr = (const float4*)(x + (size_t)rowc*128);

    float4 xa[8];
#pragma unroll
    for (int kk = 0; kk < 4; ++kk) {
        xa[kk*2]   = xr[kk*8 + q*2];
        xa[kk*2+1] = xr[kk*8 + q*2 + 1];
    }
    const float* xf = (const float*)xa;

    float as0 = 0.f, as1 = 0.f, ad0 = 0.f, ad1 = 0.f;
#pragma unroll
    for (int kk = 0; kk < 4; ++kk)
#pragma unroll
        for (int jj = 0; jj < 8; ++jj) {
            int k = kk*32 + q*8 + jj;
            float xv = xf[kk*8 + jj];
            float2 vs = vsa[k], vd = vda[k];
            as0 += xv*vs.x; as1 += xv*vs.y;
            ad0 += xv*vd.x; ad1 += xv*vd.y;
        }
#pragma unroll
    for (int o = 16; o < 64; o <<= 1) {
        as0 += __shfl_xor(as0, o); as1 += __shfl_xor(as1, o);
        ad0 += __shfl_xor(ad0, o); ad1 += __shfl_xor(ad1, o);
    }
    if (q == 0 && row < N_NODES) {
        as_out[row] = make_float2(as0, as1);
        ad_out[row] = make_float2(ad0, ad1);
    }

    bf16x8 af[4];
#pragma unroll
    for (int kk = 0; kk < 4; ++kk)
#pragma unroll
        for (int jj = 0; jj < 8; ++jj)
            af[kk][jj] = (short)f2bf(xf[kk*8 + jj]);

    __syncthreads();

    f32x4 acc[8];
#pragma unroll
    for (int cb = 0; cb < 8; ++cb) acc[cb] = (f32x4){0.f, 0.f, 0.f, 0.f};

#pragma unroll
    for (int cb = 0; cb < 8; ++cb) {
        int c = cb*16 + m;
#pragma unroll
        for (int kk = 0; kk < 4; ++kk) {
            int gs = (kk*4 + q) ^ (c & 7);
            bf16x8 bf = *(const bf16x8*)(wlds + (size_t)c*256 + gs*16);
            acc[cb] = __builtin_amdgcn_mfma_f32_16x16x32_bf16(af[kk], bf, acc[cb], 0, 0, 0);
        }
    }

#pragma unroll
    for (int cb = 0; cb < 8; ++cb)
#pragma unroll
        for (int reg = 0; reg < 4; ++reg) {
            int rr = r0 + q*4 + reg;
            if (rr < N_NODES)
                hs[(size_t)rr*128 + cb*16 + m] = f2bf(acc[cb][reg]);
        }
}

// ---- per-block partial sums of counts ----
__global__ void scan_a(P p) {
    int t = blockIdx.x / NB, j = blockIdx.x % NB;
    const int* cnt = t ? p.cnt1 : p.cnt0;
    int i = j*256 + threadIdx.x;
    int v = (i < N_NODES) ? cnt[i] : 0;
    __shared__ int sd[256];
    sd[threadIdx.x] = v; __syncthreads();
    for (int off = 128; off; off >>= 1) {
        if (threadIdx.x < off) sd[threadIdx.x] += sd[threadIdx.x + off];
        __syncthreads();
    }
    if (threadIdx.x == 0) p.bsum[t*256 + j] = sd[0];
}

// ---- merged: block-prefix of bsum (redundant per block) + per-elem scan ----
__global__ void scan_c(P p) {
    int t = blockIdx.x / NB, j = blockIdx.x % NB, tid = threadIdx.x;
    const int* cnt = t ? p.cnt1 : p.cnt0;
    int* off = t ? p.off1 : p.off0;
    int* cur = t ? p.cur1 : p.cur0;

    __shared__ int sb[256];
    int bv = (tid < NB) ? p.bsum[t*256 + tid] : 0;
    sb[tid] = bv; __syncthreads();
    for (int o = 1; o < 256; o <<= 1) {
        int u = (tid >= o) ? sb[tid - o] : 0;
        __syncthreads();
        sb[tid] += u;
        __syncthreads();
    }
    int base = (j > 0) ? sb[j-1] : 0;

    int i = j*256 + tid;
    int v = (i < N_NODES) ? cnt[i] : 0;
    __shared__ int sd[256];
    sd[tid] = v; __syncthreads();
    for (int o = 1; o < 256; o <<= 1) {
        int u = (tid >= o) ? sd[tid - o] : 0;
        __syncthreads();
        sd[tid] += u;
        __syncthreads();
    }
    if (i < N_NODES) { int ex = base + sd[tid] - v; off[i] = ex; cur[i] = ex; }
}

// ---- fill CSR slots: tuple {src, w0, w1, 0}, w = exp(leakyrelu(a_s+a_d)) ----
__global__ void fill_edges(P p) {
    int e = blockIdx.x * 256 + threadIdx.x;
    int t, ee;
    if (e < NE)        { t = 0; ee = e; }
    else if (e < 2*NE) { t = 1; ee = e - NE; }
    else return;
    const int* ei = t ? p.ei_i2u : p.ei_u2i;
    const float2* as2 = (const float2*)(t ? p.as1 : p.as0);
    const float2* ad2 = (const float2*)(t ? p.ad1 : p.ad0);
    int* cur = t ? p.cur1 : p.cur0;
    int4* et = (int4*)(t ? p.et1 : p.et0);
    int s = ei[ee], d = ei[NE + ee];
    float2 a = as2[s], b = ad2[d];
    float l0 = a.x + b.x, l1 = a.y + b.y;
    l0 = l0 >= 0.f ? l0 : 0.2f*l0;
    l1 = l1 >= 0.f ? l1 : 0.2f*l1;
    int4 v;
    v.x = s;
    v.y = __float_as_int(__expf(l0));
    v.z = __float_as_int(__expf(l1));
    v.w = 0;
    int pos = atomicAdd(&cur[d], 1);
    et[pos] = v;
}

// ---- aggregation + bias + LN + ELU ----
// 4 dsts per wave: each 16-lane group owns one complete dst (16 lanes x 8
// cols = 128). No cross-group reductions; prologue/epilogue amortized 4x.
// z is replicated within the group for free (every lane adds the same w).
__global__ __launch_bounds__(256) void aggregate(P p) {
    int lane = threadIdx.x & 63;
    int wave = threadIdx.x >> 6;
    int g = lane >> 4;       // group = dst slot 0..3
    int m = lane & 15;       // column lane: cols 8m..8m+7
    int gid = blockIdx.x*16 + wave*4 + g;
    int t = gid >= N_NODES;
    int d = gid - (t ? N_NODES : 0);
    int headhi = m >> 3;     // 0: head0 (cols<64), 1: head1
    unsigned mo = (unsigned)m * 16;   // byte offset within hs row

    const char* hs = (const char*)(t ? p.hs1b : p.hs0b);
    const int4* et = (const int4*)(t ? p.et1 : p.et0);
    int o = (t ? p.off1 : p.off0)[d];
    int n = (t ? p.cnt1 : p.cnt0)[d];

    float acc[8];
#pragma unroll
    for (int j = 0; j < 8; ++j) acc[j] = 0.f;
    float z = 0.f;

    const int4* ep = et + o;
    for (int i = 0; i < n; ++i) {
        int4 e = ep[i];
        float w = __int_as_float(headhi ? e.z : e.y);
        uint4 q = *(const uint4*)(hs + (((unsigned)e.x << 8) + mo));
        unsigned uu[4] = {q.x, q.y, q.z, q.w};
#pragma unroll
        for (int j = 0; j < 4; ++j) {
            acc[2*j]   += w * __uint_as_float(uu[j] << 16);
            acc[2*j+1] += w * __uint_as_float(uu[j] & 0xffff0000u);
        }
        z += w;
    }

    float inv = 1.f / (z + 1e-16f);
    const float* bias = t ? p.b_i2u : p.b_u2i;
    const float* lg   = t ? p.ln_g_user : p.ln_g_item;
    const float* lb   = t ? p.ln_b_user : p.ln_b_item;
    float4 bv0 = *(const float4*)(bias + m*8);
    float4 bv1 = *(const float4*)(bias + m*8 + 4);
    float bvv[8] = {bv0.x,bv0.y,bv0.z,bv0.w,bv1.x,bv1.y,bv1.z,bv1.w};
    float h[8];
#pragma unroll
    for (int j = 0; j < 8; ++j) h[j] = acc[j]*inv + bvv[j];

    // LN reductions stay inside the 16-lane group (xor 1,2,4,8)
    float s8 = 0.f;
#pragma unroll
    for (int j = 0; j < 8; ++j) s8 += h[j];
#pragma unroll
    for (int off = 1; off < 16; off <<= 1) s8 += __shfl_xor(s8, off);
    float mu = s8 * (1.f/128.f);
    float vs = 0.f;
#pragma unroll
    for (int j = 0; j < 8; ++j) { h[j] -= mu; vs += h[j]*h[j]; }
#pragma unroll
    for (int off = 1; off < 16; off <<= 1) vs += __shfl_xor(vs, off);
    float rstd = rsqrtf(vs * (1.f/128.f) + 1e-5f);

    float4 gv0 = *(const float4*)(lg + m*8);
    float4 gv1 = *(const float4*)(lg + m*8 + 4);
    float4 lb0 = *(const float4*)(lb + m*8);
    float4 lb1 = *(const float4*)(lb + m*8 + 4);
    float gvv[8] = {gv0.x,gv0.y,gv0.z,gv0.w,gv1.x,gv1.y,gv1.z,gv1.w};
    float lbb[8] = {lb0.x,lb0.y,lb0.z,lb0.w,lb1.x,lb1.y,lb1.z,lb1.w};
    float y[8];
#pragma unroll
    for (int j = 0; j < 8; ++j) {
        float v = h[j]*rstd*gvv[j] + lbb[j];
        y[j] = v > 0.f ? v : expm1f(v);
    }
    float* out = (t ? p.out_user : p.out_item) + (size_t)d*128 + m*8;
    *(float4*)out       = make_float4(y[0],y[1],y[2],y[3]);
    *(float4*)(out + 4) = make_float4(y[4],y[5],y[6],y[7]);
}

static inline char* carve(char*& cur, size_t bytes) {
    char* r = cur;
    cur += (bytes + 255) & ~(size_t)255;
    return r;
}

extern "C" void kernel_launch(void* const* d_in, const int* in_sizes, int n_in,
                              void* d_out, int out_size, void* d_ws, size_t ws_size,
                              hipStream_t stream) {
    P p;
    p.x_user      = (const float*)d_in[0];
    p.x_item      = (const float*)d_in[1];
    p.ei_u2i      = (const int*)d_in[2];
    p.ei_i2u      = (const int*)d_in[3];
    p.w_src_u2i   = (const float*)d_in[4];
    p.w_dst_u2i   = (const float*)d_in[5];
    p.att_src_u2i = (const float*)d_in[6];
    p.att_dst_u2i = (const float*)d_in[7];
    p.b_u2i       = (const float*)d_in[8];
    p.w_src_i2u   = (const float*)d_in[9];
    p.w_dst_i2u   = (const float*)d_in[10];
    p.att_src_i2u = (const float*)d_in[11];
    p.att_dst_i2u = (const float*)d_in[12];
    p.b_i2u       = (const float*)d_in[13];
    p.ln_g_user   = (const float*)d_in[14];
    p.ln_b_user   = (const float*)d_in[15];
    p.ln_g_item   = (const float*)d_in[16];
    p.ln_b_item   = (const float*)d_in[17];

    p.out_user = (float*)d_out;
    p.out_item = (float*)d_out + (size_t)N_NODES * 128;

    char* cur = (char*)d_ws;
    p.hs0b = (unsigned short*)carve(cur, (size_t)N_NODES*128*2);
    p.hs1b = (unsigned short*)carve(cur, (size_t)N_NODES*128*2);
    p.wt0  = (unsigned short*)carve(cur, 128*128*2);
    p.wt1  = (unsigned short*)carve(cur, 128*128*2);
    p.as0  = (float*)carve(cur, (size_t)N_NODES*2*4);
    p.ad0  = (float*)carve(cur, (size_t)N_NODES*2*4);
    p.as1  = (float*)carve(cur, (size_t)N_NODES*2*4);
    p.ad1  = (float*)carve(cur, (size_t)N_NODES*2*4);
    p.v_s0 = (float*)carve(cur, 256*4);
    p.v_d0 = (float*)carve(cur, 256*4);
    p.v_s1 = (float*)carve(cur, 256*4);
    p.v_d1 = (float*)carve(cur, 256*4);
    int* cnt = (int*)carve(cur, (size_t)2*N_NODES*4);
    p.cnt0 = cnt; p.cnt1 = cnt + N_NODES;
    p.off0 = (int*)carve(cur, (size_t)N_NODES*4);
    p.off1 = (int*)carve(cur, (size_t)N_NODES*4);
    p.cur0 = (int*)carve(cur, (size_t)N_NODES*4);
    p.cur1 = (int*)carve(cur, (size_t)N_NODES*4);
    p.bsum = (int*)carve(cur, 2*256*4);
    p.et0  = (int*)carve(cur, (size_t)NE*16);
    p.et1  = (int*)carve(cur, (size_t)NE*16);

    hipMemsetAsync(p.cnt0, 0, (size_t)2*N_NODES*4, stream);

    prep_count<<<6 + (2*NE + 255)/256, 256, 0, stream>>>(p);
    scan_a<<<2*NB, 256, 0, stream>>>(p);
    scan_c<<<2*NB, 256, 0, stream>>>(p);
    gemm<<<2*GB, 256, 0, stream>>>(p);
    fill_edges<<<(2*NE + 255)/256, 256, 0, stream>>>(p);
    aggregate<<<(2*N_NODES)/16, 256, 0, stream>>>(p);
}

// Round 7
// 155.110 us; speedup vs baseline: 2.0148x; 1.0506x over previous
//
#include <hip/hip_runtime.h>
#include <hip/hip_bf16.h>

#define N_NODES 50000
#define NE      400000
#define NB      196        // ceil(50000/256)
#define GB      782        // ceil(50000/64)

typedef __attribute__((ext_vector_type(8))) short bf16x8;
typedef __attribute__((ext_vector_type(4))) float f32x4;

static __device__ __forceinline__ unsigned short f2bf(float f) {
    unsigned u = __float_as_uint(f);
    unsigned r = (u + 0x7fffu + ((u >> 16) & 1u)) >> 16;
    return (unsigned short)r;
}

struct P {
    const float *x_user, *x_item;
    const int   *ei_u2i, *ei_i2u;
    const float *w_src_u2i, *w_dst_u2i, *att_src_u2i, *att_dst_u2i, *b_u2i;
    const float *w_src_i2u, *w_dst_i2u, *att_src_i2u, *att_dst_i2u, *b_i2u;
    const float *ln_g_user, *ln_b_user, *ln_g_item, *ln_b_item;
    unsigned short *hs0b, *hs1b;      // bf16 messages [N,128]
    unsigned short *wt0, *wt1;        // bf16 W^T, XOR-swizzled, [128 cols][128 k]
    // naming by EDGE TYPE: as0/ad0 for u2i (as0 idx by user, ad0 idx by item)
    //                      as1/ad1 for i2u (as1 idx by item, ad1 idx by user)
    float *as0, *ad0, *as1, *ad1;
    float *v_s0, *v_d0, *v_s1, *v_d1; // folded att vectors [128][2]
    int   *cnt0, *cnt1, *off0, *off1, *cur0, *cur1;
    int   *bsum;                      // [2*256]
    int   *et0, *et1;                 // 8B tuples {src, bf16(w1)<<16|bf16(w0)}
    float *out_user, *out_item;
};

// ---- blocks 0-3: fold v[k,h]; blocks 4-5: bf16 swizzled W^T; rest: count ----
__global__ void prep_count(P p) {
    int b = blockIdx.x, tid = threadIdx.x;
    if (b < 4) {
        const float* w   = b==0? p.w_src_u2i : b==1? p.w_dst_u2i : b==2? p.w_src_i2u : p.w_dst_i2u;
        const float* att = b==0? p.att_src_u2i : b==1? p.att_dst_u2i : b==2? p.att_src_i2u : p.att_dst_i2u;
        float* v         = b==0? p.v_s0 : b==1? p.v_d0 : b==2? p.v_s1 : p.v_d1;
        int k = tid >> 1, h = tid & 1;
        float s = 0.f;
        for (int c = 0; c < 64; ++c) s += w[k*128 + h*64 + c] * att[h*64 + c];
        v[k*2 + h] = s;
    } else if (b < 6) {
        const float* w    = (b == 4) ? p.w_src_u2i : p.w_src_i2u;
        unsigned short* wt = (b == 4) ? p.wt0 : p.wt1;
        for (int s = tid; s < 2048; s += 256) {
            int c = s >> 4, g = s & 15;
            int kg = g ^ (c & 7);
            unsigned short u[8];
#pragma unroll
            for (int j = 0; j < 8; ++j) u[j] = f2bf(w[(size_t)(kg*8 + j)*128 + c]);
            uint4 pk;
            pk.x = (unsigned)u[0] | ((unsigned)u[1] << 16);
            pk.y = (unsigned)u[2] | ((unsigned)u[3] << 16);
            pk.z = (unsigned)u[4] | ((unsigned)u[5] << 16);
            pk.w = (unsigned)u[6] | ((unsigned)u[7] << 16);
            *(uint4*)(wt + (size_t)c*128 + g*8) = pk;
        }
    } else {
        int e = (b - 6) * 256 + tid;
        if (e < NE)            atomicAdd(&p.cnt0[p.ei_u2i[NE + e]], 1);
        else if (e < 2*NE)     atomicAdd(&p.cnt1[p.ei_i2u[NE + (e - NE)]], 1);
    }
}

// ---- MFMA GEMM: hs = bf16(x @ w_src), plus fused a_s/a_d matvecs ----
// t=0: x_user -> hs0 (u2i messages), as0 (u2i a_s), ad1 (i2u a_d)
// t=1: x_item -> hs1 (i2u messages), as1 (i2u a_s), ad0 (u2i a_d)
__global__ __launch_bounds__(256) void gemm(P p) {
    int t   = blockIdx.x >= GB;
    int blk = blockIdx.x - (t ? GB : 0);
    const float* x            = t ? p.x_item : p.x_user;
    const unsigned short* wt  = t ? p.wt1 : p.wt0;
    unsigned short* hs        = t ? p.hs1b : p.hs0b;
    const float2* vsa = (const float2*)(t ? p.v_s1 : p.v_s0);
    const float2* vda = (const float2*)(t ? p.v_d0 : p.v_d1);
    float2* as_out = (float2*)(t ? p.as1 : p.as0);
    float2* ad_out = (float2*)(t ? p.ad0 : p.ad1);

    __shared__ char wlds[32768];
    int tid = threadIdx.x;
#pragma unroll
    for (int it = 0; it < 8; ++it) {
        int off = (tid + it*256) * 16;
        *(uint4*)(wlds + off) = *(const uint4*)((const char*)wt + off);
    }

    int lane = tid & 63, wave = tid >> 6;
    int q = lane >> 4, m = lane & 15;
    int r0 = blk*64 + wave*16;
    int row = r0 + m;
    int rowc = row < N_NODES ? row : N_NODES - 1;
    const float4* xr = (const float4*)(x + (size_t)rowc*128);

    float4 xa[8];
#pragma unroll
    for (int kk = 0; kk < 4; ++kk) {
        xa[kk*2]   = xr[kk*8 + q*2];
        xa[kk*2+1] = xr[kk*8 + q*2 + 1];
    }
    const float* xf = (const float*)xa;

    float as0 = 0.f, as1 = 0.f, ad0 = 0.f, ad1 = 0.f;
#pragma unroll
    for (int kk = 0; kk < 4; ++kk)
#pragma unroll
        for (int jj = 0; jj < 8; ++jj) {
            int k = kk*32 + q*8 + jj;
            float xv = xf[kk*8 + jj];
            float2 vs = vsa[k], vd = vda[k];
            as0 += xv*vs.x; as1 += xv*vs.y;
            ad0 += xv*vd.x; ad1 += xv*vd.y;
        }
#pragma unroll
    for (int o = 16; o < 64; o <<= 1) {
        as0 += __shfl_xor(as0, o); as1 += __shfl_xor(as1, o);
        ad0 += __shfl_xor(ad0, o); ad1 += __shfl_xor(ad1, o);
    }
    if (q == 0 && row < N_NODES) {
        as_out[row] = make_float2(as0, as1);
        ad_out[row] = make_float2(ad0, ad1);
    }

    bf16x8 af[4];
#pragma unroll
    for (int kk = 0; kk < 4; ++kk)
#pragma unroll
        for (int jj = 0; jj < 8; ++jj)
            af[kk][jj] = (short)f2bf(xf[kk*8 + jj]);

    __syncthreads();

    f32x4 acc[8];
#pragma unroll
    for (int cb = 0; cb < 8; ++cb) acc[cb] = (f32x4){0.f, 0.f, 0.f, 0.f};

#pragma unroll
    for (int cb = 0; cb < 8; ++cb) {
        int c = cb*16 + m;
#pragma unroll
        for (int kk = 0; kk < 4; ++kk) {
            int gs = (kk*4 + q) ^ (c & 7);
            bf16x8 bf = *(const bf16x8*)(wlds + (size_t)c*256 + gs*16);
            acc[cb] = __builtin_amdgcn_mfma_f32_16x16x32_bf16(af[kk], bf, acc[cb], 0, 0, 0);
        }
    }

#pragma unroll
    for (int cb = 0; cb < 8; ++cb)
#pragma unroll
        for (int reg = 0; reg < 4; ++reg) {
            int rr = r0 + q*4 + reg;
            if (rr < N_NODES)
                hs[(size_t)rr*128 + cb*16 + m] = f2bf(acc[cb][reg]);
        }
}

// ---- per-block partial sums of counts ----
__global__ void scan_a(P p) {
    int t = blockIdx.x / NB, j = blockIdx.x % NB;
    const int* cnt = t ? p.cnt1 : p.cnt0;
    int i = j*256 + threadIdx.x;
    int v = (i < N_NODES) ? cnt[i] : 0;
    __shared__ int sd[256];
    sd[threadIdx.x] = v; __syncthreads();
    for (int off = 128; off; off >>= 1) {
        if (threadIdx.x < off) sd[threadIdx.x] += sd[threadIdx.x + off];
        __syncthreads();
    }
    if (threadIdx.x == 0) p.bsum[t*256 + j] = sd[0];
}

// ---- merged: block-prefix of bsum (redundant per block) + per-elem scan ----
__global__ void scan_c(P p) {
    int t = blockIdx.x / NB, j = blockIdx.x % NB, tid = threadIdx.x;
    const int* cnt = t ? p.cnt1 : p.cnt0;
    int* off = t ? p.off1 : p.off0;
    int* cur = t ? p.cur1 : p.cur0;

    __shared__ int sb[256];
    int bv = (tid < NB) ? p.bsum[t*256 + tid] : 0;
    sb[tid] = bv; __syncthreads();
    for (int o = 1; o < 256; o <<= 1) {
        int u = (tid >= o) ? sb[tid - o] : 0;
        __syncthreads();
        sb[tid] += u;
        __syncthreads();
    }
    int base = (j > 0) ? sb[j-1] : 0;

    int i = j*256 + tid;
    int v = (i < N_NODES) ? cnt[i] : 0;
    __shared__ int sd[256];
    sd[tid] = v; __syncthreads();
    for (int o = 1; o < 256; o <<= 1) {
        int u = (tid >= o) ? sd[tid - o] : 0;
        __syncthreads();
        sd[tid] += u;
        __syncthreads();
    }
    if (i < N_NODES) { int ex = base + sd[tid] - v; off[i] = ex; cur[i] = ex; }
}

// ---- fill CSR slots: int2 {src, bf16(w1)<<16 | bf16(w0)} ----
__global__ void fill_edges(P p) {
    int e = blockIdx.x * 256 + threadIdx.x;
    int t, ee;
    if (e < NE)        { t = 0; ee = e; }
    else if (e < 2*NE) { t = 1; ee = e - NE; }
    else return;
    const int* ei = t ? p.ei_i2u : p.ei_u2i;
    const float2* as2 = (const float2*)(t ? p.as1 : p.as0);
    const float2* ad2 = (const float2*)(t ? p.ad1 : p.ad0);
    int* cur = t ? p.cur1 : p.cur0;
    int2* et = (int2*)(t ? p.et1 : p.et0);
    int s = ei[ee], d = ei[NE + ee];
    float2 a = as2[s], b = ad2[d];
    float l0 = a.x + b.x, l1 = a.y + b.y;
    l0 = l0 >= 0.f ? l0 : 0.2f*l0;
    l1 = l1 >= 0.f ? l1 : 0.2f*l1;
    int2 v;
    v.x = s;
    v.y = (int)(((unsigned)f2bf(__expf(l1)) << 16) | (unsigned)f2bf(__expf(l0)));
    int pos = atomicAdd(&cur[d], 1);
    et[pos] = v;
}

// ---- aggregation + bias + LN + ELU ----
// 4 dsts per wave; each 16-lane group owns one dst (16 lanes x 8 cols).
// Edge loop unrolled x4 with batched independent loads for MLP.
__global__ __launch_bounds__(256) void aggregate(P p) {
    int lane = threadIdx.x & 63;
    int wave = threadIdx.x >> 6;
    int g = lane >> 4;       // group = dst slot 0..3
    int m = lane & 15;       // column lane: cols 8m..8m+7
    int gid = blockIdx.x*16 + wave*4 + g;
    int t = gid >= N_NODES;
    int d = gid - (t ? N_NODES : 0);
    int headhi = m >> 3;     // 0: head0 (cols<64), 1: head1
    unsigned mo = (unsigned)m * 16;   // byte offset within hs row

    const char* hs = (const char*)(t ? p.hs1b : p.hs0b);
    const int2* et = (const int2*)(t ? p.et1 : p.et0);
    int o = (t ? p.off1 : p.off0)[d];
    int n = (t ? p.cnt1 : p.cnt0)[d];

    float acc[8];
#pragma unroll
    for (int j = 0; j < 8; ++j) acc[j] = 0.f;
    float z = 0.f;

    const int2* ep = et + o;

#define WSEL(ey) __uint_as_float(headhi ? ((unsigned)(ey) & 0xffff0000u) : ((unsigned)(ey) << 16))
#define ACC8(qq, ww) { \
        unsigned uu0=(qq).x, uu1=(qq).y, uu2=(qq).z, uu3=(qq).w; \
        acc[0] += (ww) * __uint_as_float(uu0 << 16); \
        acc[1] += (ww) * __uint_as_float(uu0 & 0xffff0000u); \
        acc[2] += (ww) * __uint_as_float(uu1 << 16); \
        acc[3] += (ww) * __uint_as_float(uu1 & 0xffff0000u); \
        acc[4] += (ww) * __uint_as_float(uu2 << 16); \
        acc[5] += (ww) * __uint_as_float(uu2 & 0xffff0000u); \
        acc[6] += (ww) * __uint_as_float(uu3 << 16); \
        acc[7] += (ww) * __uint_as_float(uu3 & 0xffff0000u); }

    int i = 0;
    for (; i + 4 <= n; i += 4) {
        int2 e0 = ep[i], e1 = ep[i+1], e2 = ep[i+2], e3 = ep[i+3];
        uint4 q0 = *(const uint4*)(hs + (((unsigned)e0.x << 8) + mo));
        uint4 q1 = *(const uint4*)(hs + (((unsigned)e1.x << 8) + mo));
        uint4 q2 = *(const uint4*)(hs + (((unsigned)e2.x << 8) + mo));
        uint4 q3 = *(const uint4*)(hs + (((unsigned)e3.x << 8) + mo));
        float w0 = WSEL(e0.y), w1 = WSEL(e1.y), w2 = WSEL(e2.y), w3 = WSEL(e3.y);
        ACC8(q0, w0); ACC8(q1, w1); ACC8(q2, w2); ACC8(q3, w3);
        z += w0 + w1 + w2 + w3;
    }
    for (; i < n; ++i) {
        int2 e0 = ep[i];
        uint4 q0 = *(const uint4*)(hs + (((unsigned)e0.x << 8) + mo));
        float w0 = WSEL(e0.y);
        ACC8(q0, w0);
        z += w0;
    }
#undef WSEL
#undef ACC8

    float inv = 1.f / (z + 1e-16f);
    const float* bias = t ? p.b_i2u : p.b_u2i;
    const float* lg   = t ? p.ln_g_user : p.ln_g_item;
    const float* lb   = t ? p.ln_b_user : p.ln_b_item;
    float4 bv0 = *(const float4*)(bias + m*8);
    float4 bv1 = *(const float4*)(bias + m*8 + 4);
    float bvv[8] = {bv0.x,bv0.y,bv0.z,bv0.w,bv1.x,bv1.y,bv1.z,bv1.w};
    float h[8];
#pragma unroll
    for (int j = 0; j < 8; ++j) h[j] = acc[j]*inv + bvv[j];

    // LN reductions stay inside the 16-lane group (xor 1,2,4,8)
    float s8 = 0.f;
#pragma unroll
    for (int j = 0; j < 8; ++j) s8 += h[j];
#pragma unroll
    for (int off = 1; off < 16; off <<= 1) s8 += __shfl_xor(s8, off);
    float mu = s8 * (1.f/128.f);
    float vs = 0.f;
#pragma unroll
    for (int j = 0; j < 8; ++j) { h[j] -= mu; vs += h[j]*h[j]; }
#pragma unroll
    for (int off = 1; off < 16; off <<= 1) vs += __shfl_xor(vs, off);
    float rstd = rsqrtf(vs * (1.f/128.f) + 1e-5f);

    float4 gv0 = *(const float4*)(lg + m*8);
    float4 gv1 = *(const float4*)(lg + m*8 + 4);
    float4 lb0 = *(const float4*)(lb + m*8);
    float4 lb1 = *(const float4*)(lb + m*8 + 4);
    float gvv[8] = {gv0.x,gv0.y,gv0.z,gv0.w,gv1.x,gv1.y,gv1.z,gv1.w};
    float lbb[8] = {lb0.x,lb0.y,lb0.z,lb0.w,lb1.x,lb1.y,lb1.z,lb1.w};
    float y[8];
#pragma unroll
    for (int j = 0; j < 8; ++j) {
        float v = h[j]*rstd*gvv[j] + lbb[j];
        y[j] = v > 0.f ? v : expm1f(v);
    }
    float* out = (t ? p.out_user : p.out_item) + (size_t)d*128 + m*8;
    *(float4*)out       = make_float4(y[0],y[1],y[2],y[3]);
    *(float4*)(out + 4) = make_float4(y[4],y[5],y[6],y[7]);
}

static inline char* carve(char*& cur, size_t bytes) {
    char* r = cur;
    cur += (bytes + 255) & ~(size_t)255;
    return r;
}

extern "C" void kernel_launch(void* const* d_in, const int* in_sizes, int n_in,
                              void* d_out, int out_size, void* d_ws, size_t ws_size,
                              hipStream_t stream) {
    P p;
    p.x_user      = (const float*)d_in[0];
    p.x_item      = (const float*)d_in[1];
    p.ei_u2i      = (const int*)d_in[2];
    p.ei_i2u      = (const int*)d_in[3];
    p.w_src_u2i   = (const float*)d_in[4];
    p.w_dst_u2i   = (const float*)d_in[5];
    p.att_src_u2i = (const float*)d_in[6];
    p.att_dst_u2i = (const float*)d_in[7];
    p.b_u2i       = (const float*)d_in[8];
    p.w_src_i2u   = (const float*)d_in[9];
    p.w_dst_i2u   = (const float*)d_in[10];
    p.att_src_i2u = (const float*)d_in[11];
    p.att_dst_i2u = (const float*)d_in[12];
    p.b_i2u       = (const float*)d_in[13];
    p.ln_g_user   = (const float*)d_in[14];
    p.ln_b_user   = (const float*)d_in[15];
    p.ln_g_item   = (const float*)d_in[16];
    p.ln_b_item   = (const float*)d_in[17];

    p.out_user = (float*)d_out;
    p.out_item = (float*)d_out + (size_t)N_NODES * 128;

    char* cur = (char*)d_ws;
    p.hs0b = (unsigned short*)carve(cur, (size_t)N_NODES*128*2);
    p.hs1b = (unsigned short*)carve(cur, (size_t)N_NODES*128*2);
    p.wt0  = (unsigned short*)carve(cur, 128*128*2);
    p.wt1  = (unsigned short*)carve(cur, 128*128*2);
    p.as0  = (float*)carve(cur, (size_t)N_NODES*2*4);
    p.ad0  = (float*)carve(cur, (size_t)N_NODES*2*4);
    p.as1  = (float*)carve(cur, (size_t)N_NODES*2*4);
    p.ad1  = (float*)carve(cur, (size_t)N_NODES*2*4);
    p.v_s0 = (float*)carve(cur, 256*4);
    p.v_d0 = (float*)carve(cur, 256*4);
    p.v_s1 = (float*)carve(cur, 256*4);
    p.v_d1 = (float*)carve(cur, 256*4);
    int* cnt = (int*)carve(cur, (size_t)2*N_NODES*4);
    p.cnt0 = cnt; p.cnt1 = cnt + N_NODES;
    p.off0 = (int*)carve(cur, (size_t)N_NODES*4);
    p.off1 = (int*)carve(cur, (size_t)N_NODES*4);
    p.cur0 = (int*)carve(cur, (size_t)N_NODES*4);
    p.cur1 = (int*)carve(cur, (size_t)N_NODES*4);
    p.bsum = (int*)carve(cur, 2*256*4);
    p.et0  = (int*)carve(cur, (size_t)NE*8);
    p.et1  = (int*)carve(cur, (size_t)NE*8);

    hipMemsetAsync(p.cnt0, 0, (size_t)2*N_NODES*4, stream);

    prep_count<<<6 + (2*NE + 255)/256, 256, 0, stream>>>(p);
    scan_a<<<2*NB, 256, 0, stream>>>(p);
    scan_c<<<2*NB, 256, 0, stream>>>(p);
    gemm<<<2*GB, 256, 0, stream>>>(p);
    fill_edges<<<(2*NE + 255)/256, 256, 0, stream>>>(p);
    aggregate<<<(2*N_NODES)/16, 256, 0, stream>>>(p);
}

// Round 8
// 123.419 us; speedup vs baseline: 2.5321x; 1.2568x over previous
//
#include <hip/hip_runtime.h>
#include <hip/hip_bf16.h>

#define N_NODES 50000
#define NE      400000
#define NB      196        // ceil(50000/256)
#define GB      782        // ceil(50000/64)

typedef __attribute__((ext_vector_type(8))) short bf16x8;
typedef __attribute__((ext_vector_type(4))) float f32x4;

static __device__ __forceinline__ unsigned short f2bf(float f) {
    unsigned u = __float_as_uint(f);
    unsigned r = (u + 0x7fffu + ((u >> 16) & 1u)) >> 16;
    return (unsigned short)r;
}

struct P {
    const float *x_user, *x_item;
    const int   *ei_u2i, *ei_i2u;
    const float *w_src_u2i, *w_dst_u2i, *att_src_u2i, *att_dst_u2i, *b_u2i;
    const float *w_src_i2u, *w_dst_i2u, *att_src_i2u, *att_dst_i2u, *b_i2u;
    const float *ln_g_user, *ln_b_user, *ln_g_item, *ln_b_item;
    unsigned short *hs0b, *hs1b;      // bf16 messages [N,128]
    unsigned short *wt0, *wt1;        // bf16 W^T, XOR-swizzled, [128 cols][128 k]
    // naming by EDGE TYPE: as0/ad0 for u2i (as0 idx by user, ad0 idx by item)
    //                      as1/ad1 for i2u (as1 idx by item, ad1 idx by user)
    float *as0, *ad0, *as1, *ad1;
    float *v_s0, *v_d0, *v_s1, *v_d1; // folded att vectors [128][2]
    int   *cnt0, *cnt1, *off0, *off1;
    int   *bsum;                      // [2*256]
    unsigned short *rank0, *rank1;    // per-edge rank within dst (u16)
    unsigned short *s0, *s1;          // CSR src indices (u16)
    float *out_user, *out_item;
};

// ---- blocks 0-3: fold v[k,h]; 4-5: bf16 swizzled W^T; rest: count+rank ----
__global__ void prep_count(P p) {
    int b = blockIdx.x, tid = threadIdx.x;
    if (b < 4) {
        const float* w   = b==0? p.w_src_u2i : b==1? p.w_dst_u2i : b==2? p.w_src_i2u : p.w_dst_i2u;
        const float* att = b==0? p.att_src_u2i : b==1? p.att_dst_u2i : b==2? p.att_src_i2u : p.att_dst_i2u;
        float* v         = b==0? p.v_s0 : b==1? p.v_d0 : b==2? p.v_s1 : p.v_d1;
        int k = tid >> 1, h = tid & 1;
        float s = 0.f;
        for (int c = 0; c < 64; ++c) s += w[k*128 + h*64 + c] * att[h*64 + c];
        v[k*2 + h] = s;
    } else if (b < 6) {
        const float* w    = (b == 4) ? p.w_src_u2i : p.w_src_i2u;
        unsigned short* wt = (b == 4) ? p.wt0 : p.wt1;
        for (int s = tid; s < 2048; s += 256) {
            int c = s >> 4, g = s & 15;
            int kg = g ^ (c & 7);
            unsigned short u[8];
#pragma unroll
            for (int j = 0; j < 8; ++j) u[j] = f2bf(w[(size_t)(kg*8 + j)*128 + c]);
            uint4 pk;
            pk.x = (unsigned)u[0] | ((unsigned)u[1] << 16);
            pk.y = (unsigned)u[2] | ((unsigned)u[3] << 16);
            pk.z = (unsigned)u[4] | ((unsigned)u[5] << 16);
            pk.w = (unsigned)u[6] | ((unsigned)u[7] << 16);
            *(uint4*)(wt + (size_t)c*128 + g*8) = pk;
        }
    } else {
        int e = (b - 6) * 256 + tid;
        if (e < NE) {
            int d = p.ei_u2i[NE + e];
            int r = atomicAdd(&p.cnt0[d], 1);
            p.rank0[e] = (unsigned short)r;
        } else if (e < 2*NE) {
            int ee = e - NE;
            int d = p.ei_i2u[NE + ee];
            int r = atomicAdd(&p.cnt1[d], 1);
            p.rank1[ee] = (unsigned short)r;
        }
    }
}

// ---- merged: blocks [0,2*NB) run scan_a; the rest run the MFMA GEMM ----
// GEMM: hs = bf16(x @ w_src), plus fused a_s/a_d matvecs
// t=0: x_user -> hs0, as0, ad1;  t=1: x_item -> hs1, as1, ad0
__global__ __launch_bounds__(256) void gemm_scan(P p) {
    __shared__ char wlds[32768];
    int tid = threadIdx.x;

    if (blockIdx.x < 2*NB) {
        int t = blockIdx.x / NB, j = blockIdx.x % NB;
        const int* cnt = t ? p.cnt1 : p.cnt0;
        int i = j*256 + tid;
        int v = (i < N_NODES) ? cnt[i] : 0;
        int* sd = (int*)wlds;
        sd[tid] = v; __syncthreads();
        for (int off = 128; off; off >>= 1) {
            if (tid < off) sd[tid] += sd[tid + off];
            __syncthreads();
        }
        if (tid == 0) p.bsum[t*256 + j] = sd[0];
        return;
    }

    int bb  = blockIdx.x - 2*NB;
    int t   = bb >= GB;
    int blk = bb - (t ? GB : 0);
    const float* x            = t ? p.x_item : p.x_user;
    const unsigned short* wt  = t ? p.wt1 : p.wt0;
    unsigned short* hs        = t ? p.hs1b : p.hs0b;
    const float2* vsa = (const float2*)(t ? p.v_s1 : p.v_s0);
    const float2* vda = (const float2*)(t ? p.v_d0 : p.v_d1);
    float2* as_out = (float2*)(t ? p.as1 : p.as0);
    float2* ad_out = (float2*)(t ? p.ad0 : p.ad1);

#pragma unroll
    for (int it = 0; it < 8; ++it) {
        int off = (tid + it*256) * 16;
        *(uint4*)(wlds + off) = *(const uint4*)((const char*)wt + off);
    }

    int lane = tid & 63, wave = tid >> 6;
    int q = lane >> 4, m = lane & 15;
    int r0 = blk*64 + wave*16;
    int row = r0 + m;
    int rowc = row < N_NODES ? row : N_NODES - 1;
    const float4* xr = (const float4*)(x + (size_t)rowc*128);

    float4 xa[8];
#pragma unroll
    for (int kk = 0; kk < 4; ++kk) {
        xa[kk*2]   = xr[kk*8 + q*2];
        xa[kk*2+1] = xr[kk*8 + q*2 + 1];
    }
    const float* xf = (const float*)xa;

    float as0 = 0.f, as1 = 0.f, ad0 = 0.f, ad1 = 0.f;
#pragma unroll
    for (int kk = 0; kk < 4; ++kk)
#pragma unroll
        for (int jj = 0; jj < 8; ++jj) {
            int k = kk*32 + q*8 + jj;
            float xv = xf[kk*8 + jj];
            float2 vs = vsa[k], vd = vda[k];
            as0 += xv*vs.x; as1 += xv*vs.y;
            ad0 += xv*vd.x; ad1 += xv*vd.y;
        }
#pragma unroll
    for (int o = 16; o < 64; o <<= 1) {
        as0 += __shfl_xor(as0, o); as1 += __shfl_xor(as1, o);
        ad0 += __shfl_xor(ad0, o); ad1 += __shfl_xor(ad1, o);
    }
    if (q == 0 && row < N_NODES) {
        as_out[row] = make_float2(as0, as1);
        ad_out[row] = make_float2(ad0, ad1);
    }

    bf16x8 af[4];
#pragma unroll
    for (int kk = 0; kk < 4; ++kk)
#pragma unroll
        for (int jj = 0; jj < 8; ++jj)
            af[kk][jj] = (short)f2bf(xf[kk*8 + jj]);

    __syncthreads();

    f32x4 acc[8];
#pragma unroll
    for (int cb = 0; cb < 8; ++cb) acc[cb] = (f32x4){0.f, 0.f, 0.f, 0.f};

#pragma unroll
    for (int cb = 0; cb < 8; ++cb) {
        int c = cb*16 + m;
#pragma unroll
        for (int kk = 0; kk < 4; ++kk) {
            int gs = (kk*4 + q) ^ (c & 7);
            bf16x8 bf = *(const bf16x8*)(wlds + (size_t)c*256 + gs*16);
            acc[cb] = __builtin_amdgcn_mfma_f32_16x16x32_bf16(af[kk], bf, acc[cb], 0, 0, 0);
        }
    }

#pragma unroll
    for (int cb = 0; cb < 8; ++cb)
#pragma unroll
        for (int reg = 0; reg < 4; ++reg) {
            int rr = r0 + q*4 + reg;
            if (rr < N_NODES)
                hs[(size_t)rr*128 + cb*16 + m] = f2bf(acc[cb][reg]);
        }
}

// ---- merged: block-prefix of bsum (redundant per block) + per-elem scan ----
__global__ void scan_c(P p) {
    int t = blockIdx.x / NB, j = blockIdx.x % NB, tid = threadIdx.x;
    const int* cnt = t ? p.cnt1 : p.cnt0;
    int* off = t ? p.off1 : p.off0;

    __shared__ int sb[256];
    int bv = (tid < NB) ? p.bsum[t*256 + tid] : 0;
    sb[tid] = bv; __syncthreads();
    for (int o = 1; o < 256; o <<= 1) {
        int u = (tid >= o) ? sb[tid - o] : 0;
        __syncthreads();
        sb[tid] += u;
        __syncthreads();
    }
    int base = (j > 0) ? sb[j-1] : 0;

    int i = j*256 + tid;
    int v = (i < N_NODES) ? cnt[i] : 0;
    __shared__ int sd[256];
    sd[tid] = v; __syncthreads();
    for (int o = 1; o < 256; o <<= 1) {
        int u = (tid >= o) ? sd[tid - o] : 0;
        __syncthreads();
        sd[tid] += u;
        __syncthreads();
    }
    if (i < N_NODES) off[i] = base + sd[tid] - v;
}

// ---- fill CSR slots: srcs[off[d] + rank[e]] = u16 src. No atomics. ----
__global__ void fill_edges(P p) {
    int e = blockIdx.x * 256 + threadIdx.x;
    int t, ee;
    if (e < NE)        { t = 0; ee = e; }
    else if (e < 2*NE) { t = 1; ee = e - NE; }
    else return;
    const int* ei = t ? p.ei_i2u : p.ei_u2i;
    const int* off = t ? p.off1 : p.off0;
    const unsigned short* rank = t ? p.rank1 : p.rank0;
    unsigned short* srcs = t ? p.s1 : p.s0;
    int s = ei[ee], d = ei[NE + ee];
    int pos = off[d] + (int)rank[ee];
    srcs[pos] = (unsigned short)s;
}

// ---- aggregation + weight recompute + bias + LN + ELU ----
// 4 dsts per wave; each 16-lane group owns one dst (16 lanes x 8 cols).
// Edge loop unrolled x4 with batched independent loads (srcs -> as2 & hs).
__global__ __launch_bounds__(256) void aggregate(P p) {
    int lane = threadIdx.x & 63;
    int wave = threadIdx.x >> 6;
    int g = lane >> 4;       // group = dst slot 0..3
    int m = lane & 15;       // column lane: cols 8m..8m+7
    int gid = blockIdx.x*16 + wave*4 + g;
    int t = gid >= N_NODES;
    int d = gid - (t ? N_NODES : 0);
    int headhi = m >> 3;     // 0: head0 (cols<64), 1: head1
    unsigned mo = (unsigned)m * 16;   // byte offset within hs row

    const char* hs = (const char*)(t ? p.hs1b : p.hs0b);
    const unsigned short* srcs = t ? p.s1 : p.s0;
    const float2* as2 = (const float2*)(t ? p.as1 : p.as0);
    const float2* ad2 = (const float2*)(t ? p.ad1 : p.ad0);
    int o = (t ? p.off1 : p.off0)[d];
    int n = (t ? p.cnt1 : p.cnt0)[d];

    float2 adv = ad2[d];
    float adh = headhi ? adv.y : adv.x;

    float acc[8];
#pragma unroll
    for (int j = 0; j < 8; ++j) acc[j] = 0.f;
    float z = 0.f;

    const unsigned short* sp = srcs + o;

#define ACC8(qq, ww) { \
        unsigned uu0=(qq).x, uu1=(qq).y, uu2=(qq).z, uu3=(qq).w; \
        acc[0] += (ww) * __uint_as_float(uu0 << 16); \
        acc[1] += (ww) * __uint_as_float(uu0 & 0xffff0000u); \
        acc[2] += (ww) * __uint_as_float(uu1 << 16); \
        acc[3] += (ww) * __uint_as_float(uu1 & 0xffff0000u); \
        acc[4] += (ww) * __uint_as_float(uu2 << 16); \
        acc[5] += (ww) * __uint_as_float(uu2 & 0xffff0000u); \
        acc[6] += (ww) * __uint_as_float(uu3 << 16); \
        acc[7] += (ww) * __uint_as_float(uu3 & 0xffff0000u); }
#define WCOMP(aa) __expf(fmaxf(((headhi ? (aa).y : (aa).x) + adh), 0.2f*((headhi ? (aa).y : (aa).x) + adh)))

    int i = 0;
    for (; i + 4 <= n; i += 4) {
        unsigned sA = sp[i], sB = sp[i+1], sC = sp[i+2], sD = sp[i+3];
        float2 aA = as2[sA], aB = as2[sB], aC = as2[sC], aD = as2[sD];
        uint4 qA = *(const uint4*)(hs + ((sA << 8) + mo));
        uint4 qB = *(const uint4*)(hs + ((sB << 8) + mo));
        uint4 qC = *(const uint4*)(hs + ((sC << 8) + mo));
        uint4 qD = *(const uint4*)(hs + ((sD << 8) + mo));
        float wA = WCOMP(aA), wB = WCOMP(aB), wC = WCOMP(aC), wD = WCOMP(aD);
        ACC8(qA, wA); ACC8(qB, wB); ACC8(qC, wC); ACC8(qD, wD);
        z += wA + wB + wC + wD;
    }
    for (; i < n; ++i) {
        unsigned sA = sp[i];
        float2 aA = as2[sA];
        uint4 qA = *(const uint4*)(hs + ((sA << 8) + mo));
        float wA = WCOMP(aA);
        ACC8(qA, wA);
        z += wA;
    }
#undef ACC8
#undef WCOMP

    float inv = 1.f / (z + 1e-16f);
    const float* bias = t ? p.b_i2u : p.b_u2i;
    const float* lg   = t ? p.ln_g_user : p.ln_g_item;
    const float* lb   = t ? p.ln_b_user : p.ln_b_item;
    float4 bv0 = *(const float4*)(bias + m*8);
    float4 bv1 = *(const float4*)(bias + m*8 + 4);
    float bvv[8] = {bv0.x,bv0.y,bv0.z,bv0.w,bv1.x,bv1.y,bv1.z,bv1.w};
    float h[8];
#pragma unroll
    for (int j = 0; j < 8; ++j) h[j] = acc[j]*inv + bvv[j];

    // LN reductions stay inside the 16-lane group (xor 1,2,4,8)
    float s8 = 0.f;
#pragma unroll
    for (int j = 0; j < 8; ++j) s8 += h[j];
#pragma unroll
    for (int off = 1; off < 16; off <<= 1) s8 += __shfl_xor(s8, off);
    float mu = s8 * (1.f/128.f);
    float vs = 0.f;
#pragma unroll
    for (int j = 0; j < 8; ++j) { h[j] -= mu; vs += h[j]*h[j]; }
#pragma unroll
    for (int off = 1; off < 16; off <<= 1) vs += __shfl_xor(vs, off);
    float rstd = rsqrtf(vs * (1.f/128.f) + 1e-5f);

    float4 gv0 = *(const float4*)(lg + m*8);
    float4 gv1 = *(const float4*)(lg + m*8 + 4);
    float4 lb0 = *(const float4*)(lb + m*8);
    float4 lb1 = *(const float4*)(lb + m*8 + 4);
    float gvv[8] = {gv0.x,gv0.y,gv0.z,gv0.w,gv1.x,gv1.y,gv1.z,gv1.w};
    float lbb[8] = {lb0.x,lb0.y,lb0.z,lb0.w,lb1.x,lb1.y,lb1.z,lb1.w};
    float y[8];
#pragma unroll
    for (int j = 0; j < 8; ++j) {
        float v = h[j]*rstd*gvv[j] + lbb[j];
        y[j] = v > 0.f ? v : expm1f(v);
    }
    float* out = (t ? p.out_user : p.out_item) + (size_t)d*128 + m*8;
    *(float4*)out       = make_float4(y[0],y[1],y[2],y[3]);
    *(float4*)(out + 4) = make_float4(y[4],y[5],y[6],y[7]);
}

static inline char* carve(char*& cur, size_t bytes) {
    char* r = cur;
    cur += (bytes + 255) & ~(size_t)255;
    return r;
}

extern "C" void kernel_launch(void* const* d_in, const int* in_sizes, int n_in,
                              void* d_out, int out_size, void* d_ws, size_t ws_size,
                              hipStream_t stream) {
    P p;
    p.x_user      = (const float*)d_in[0];
    p.x_item      = (const float*)d_in[1];
    p.ei_u2i      = (const int*)d_in[2];
    p.ei_i2u      = (const int*)d_in[3];
    p.w_src_u2i   = (const float*)d_in[4];
    p.w_dst_u2i   = (const float*)d_in[5];
    p.att_src_u2i = (const float*)d_in[6];
    p.att_dst_u2i = (const float*)d_in[7];
    p.b_u2i       = (const float*)d_in[8];
    p.w_src_i2u   = (const float*)d_in[9];
    p.w_dst_i2u   = (const float*)d_in[10];
    p.att_src_i2u = (const float*)d_in[11];
    p.att_dst_i2u = (const float*)d_in[12];
    p.b_i2u       = (const float*)d_in[13];
    p.ln_g_user   = (const float*)d_in[14];
    p.ln_b_user   = (const float*)d_in[15];
    p.ln_g_item   = (const float*)d_in[16];
    p.ln_b_item   = (const float*)d_in[17];

    p.out_user = (float*)d_out;
    p.out_item = (float*)d_out + (size_t)N_NODES * 128;

    char* cur = (char*)d_ws;
    p.hs0b = (unsigned short*)carve(cur, (size_t)N_NODES*128*2);
    p.hs1b = (unsigned short*)carve(cur, (size_t)N_NODES*128*2);
    p.wt0  = (unsigned short*)carve(cur, 128*128*2);
    p.wt1  = (unsigned short*)carve(cur, 128*128*2);
    p.as0  = (float*)carve(cur, (size_t)N_NODES*2*4);
    p.ad0  = (float*)carve(cur, (size_t)N_NODES*2*4);
    p.as1  = (float*)carve(cur, (size_t)N_NODES*2*4);
    p.ad1  = (float*)carve(cur, (size_t)N_NODES*2*4);
    p.v_s0 = (float*)carve(cur, 256*4);
    p.v_d0 = (float*)carve(cur, 256*4);
    p.v_s1 = (float*)carve(cur, 256*4);
    p.v_d1 = (float*)carve(cur, 256*4);
    int* cnt = (int*)carve(cur, (size_t)2*N_NODES*4);
    p.cnt0 = cnt; p.cnt1 = cnt + N_NODES;
    p.off0 = (int*)carve(cur, (size_t)N_NODES*4);
    p.off1 = (int*)carve(cur, (size_t)N_NODES*4);
    p.bsum = (int*)carve(cur, 2*256*4);
    p.rank0 = (unsigned short*)carve(cur, (size_t)NE*2);
    p.rank1 = (unsigned short*)carve(cur, (size_t)NE*2);
    p.s0   = (unsigned short*)carve(cur, (size_t)NE*2);
    p.s1   = (unsigned short*)carve(cur, (size_t)NE*2);

    hipMemsetAsync(p.cnt0, 0, (size_t)2*N_NODES*4, stream);

    prep_count<<<6 + (2*NE + 255)/256, 256, 0, stream>>>(p);
    gemm_scan<<<2*NB + 2*GB, 256, 0, stream>>>(p);
    scan_c<<<2*NB, 256, 0, stream>>>(p);
    fill_edges<<<(2*NE + 255)/256, 256, 0, stream>>>(p);
    aggregate<<<(2*N_NODES)/16, 256, 0, stream>>>(p);
}